// Round 1
// baseline (1155.496 us; speedup 1.0000x reference)
//
#include <hip/hip_runtime.h>
#include <math.h>

// ---------------- workspace layout (float offsets) ----------------
#define WS_OFF_L2      0            // 2*256*64*64 = 2097152   (reused as f2_chw)
#define WS_OFF_L3      2097152      // 524288                  (reused as f3_chw)
#define WS_OFF_H1_2    2621440      // 2097152
#define WS_OFF_H1_3    4718592      // 524288
#define WS_OFF_H1_4    5242880      // 131072
#define WS_OFF_F4      5373952      // 131072 (f4_chw)
#define WS_OFF_FH2     5505024      // 2097152 (f2 hwc)
#define WS_OFF_FH3     7602176      // 524288
#define WS_OFF_FH4     8126464      // 131072
#define WS_OFF_RPNW    8257536      // 64*2304 = 147456
#define WS_OFF_INV1    8404992
#define WS_OFF_BETA1   8405248
#define WS_OFF_INV2    8405504
#define WS_OFF_BETA2   8405760
#define WS_OFF_LOGITS  8406016      // 2*16128
#define WS_OFF_TVALS   8438272      // 2*16128*4
#define WS_OFF_SKEY    8567296      // 2*16128 (u32)
#define WS_OFF_COORDS  8599552      // 2*3*32*5 (int)
// total 8600512 floats = 34.4 MB

// out layout: dets[2][3][32][5] @0 (960) | mask[2][3][32] @960 (192) | rois[2][3][32][256][7][7] @1152

// ---------------- prep: BN fold + padded RPN weights ----------------
__global__ __launch_bounds__(256) void prep_kernel(
    const float* __restrict__ hg1, const float* __restrict__ hb1,
    const float* __restrict__ hm1, const float* __restrict__ hv1,
    const float* __restrict__ hg2, const float* __restrict__ hb2,
    const float* __restrict__ hm2, const float* __restrict__ hv2,
    const float* __restrict__ clsw, const float* __restrict__ locw,
    float* __restrict__ ws)
{
  int t = blockIdx.x * 256 + threadIdx.x;
  if (t < 256) {
    float i1 = (float)((double)hg1[t] / sqrt((double)hv1[t] + 1e-5));
    ws[WS_OFF_INV1 + t] = i1;
    ws[WS_OFF_BETA1 + t] = hb1[t] - hm1[t] * i1;
    float i2 = (float)((double)hg2[t] / sqrt((double)hv2[t] + 1e-5));
    ws[WS_OFF_INV2 + t] = i2;
    ws[WS_OFF_BETA2 + t] = hb2[t] - hm2[t] * i2;
  }
  for (int e = t; e < 64 * 2304; e += gridDim.x * 256) {
    int oc = e / 2304, k = e - oc * 2304;
    float v = 0.f;
    if (oc < 3) v = clsw[oc * 2304 + k];
    else if (oc < 15) v = locw[(oc - 3) * 2304 + k];
    ws[WS_OFF_RPNW + e] = v;
  }
}

// ---------------- FPN merge: out = a + upsample2x(b) ----------------
__global__ __launch_bounds__(256) void merge_up2_kernel(
    const float* __restrict__ a, const float* __restrict__ b,
    float* __restrict__ out, int H, int total)
{
  int i = blockIdx.x * 256 + threadIdx.x;
  if (i >= total) return;
  int x = i % H;
  int y = (i / H) % H;
  int nc = i / (H * H);
  int Hh = H >> 1;
  out[i] = a[i] + b[(size_t)nc * Hh * Hh + (y >> 1) * Hh + (x >> 1)];
}

// ---------------- tiled 3x3 conv, IC=256, 64-oc tile ----------------
struct ConvArgs {
  const float* in0; const float* in1; const float* in2;   // per-level inputs (CHW, per-img offset applied in kernel)
  float* out0; float* out1; float* out2;                  // CHW outs (mode 0)
  float* hwc0; float* hwc1; float* hwc2;                  // HWC outs or null
  const float* W;                                         // [OC][256][9]
  const float* inv; const float* beta;                    // BN folded (mode 0)
  float* logits; float* tvals;                            // mode 1 outputs
  int mode;                                               // 0 head, 1 rpn
};

__global__ __launch_bounds__(256) void conv3x3_kernel(ConvArgs a)
{
  __shared__ float P[800];        // 8 ic x 10 x 10 patch
  __shared__ float Ws[64 * 73];   // 64 oc x 72 (pad 73)
  int bt = blockIdx.x;
  int lvl, tile;
  if (bt < 64) { lvl = 0; tile = bt; }
  else if (bt < 80) { lvl = 1; tile = bt - 64; }
  else { lvl = 2; tile = bt - 80; }
  int H = (lvl == 0) ? 64 : ((lvl == 1) ? 32 : 16);
  int HW = H * H;
  int tpr = H >> 3;
  int ty0 = (tile / tpr) * 8, tx0 = (tile % tpr) * 8;
  int img = blockIdx.z;
  int ocbase = blockIdx.y * 64;
  const float* inp = ((lvl == 0) ? a.in0 : ((lvl == 1) ? a.in1 : a.in2)) + (size_t)img * 256 * HW;
  int tx = threadIdx.x;
  int oc_t = tx & 15, px_t = tx >> 4;
  int rr = px_t >> 1, cc = (px_t & 1) * 4;
  float acc[4][4];
  #pragma unroll
  for (int o = 0; o < 4; ++o)
    #pragma unroll
    for (int p = 0; p < 4; ++p) acc[o][p] = 0.f;

  for (int ic0 = 0; ic0 < 256; ic0 += 8) {
    for (int e = tx; e < 800; e += 256) {
      int ic = e / 100; int rem = e - ic * 100;
      int py = rem / 10; int pxx = rem - py * 10;
      int gy = ty0 + py - 1, gx = tx0 + pxx - 1;
      float v = 0.f;
      if ((unsigned)gy < (unsigned)H && (unsigned)gx < (unsigned)H)
        v = inp[(size_t)(ic0 + ic) * HW + gy * H + gx];
      P[e] = v;
    }
    for (int e = tx; e < 4608; e += 256) {
      int oc = e / 72; int r = e - oc * 72;
      Ws[oc * 73 + r] = a.W[(size_t)(ocbase + oc) * 2304 + ic0 * 9 + r];
    }
    __syncthreads();
    #pragma unroll 1
    for (int ic = 0; ic < 8; ++ic) {
      float pin[3][6];
      #pragma unroll
      for (int dy = 0; dy < 3; ++dy)
        #pragma unroll
        for (int j = 0; j < 6; ++j)
          pin[dy][j] = P[ic * 100 + (rr + dy) * 10 + cc + j];
      const float* wp = &Ws[(oc_t * 4) * 73 + ic * 9];
      #pragma unroll
      for (int o = 0; o < 4; ++o)
        #pragma unroll
        for (int dy = 0; dy < 3; ++dy)
          #pragma unroll
          for (int dx = 0; dx < 3; ++dx) {
            float w = wp[o * 73 + dy * 3 + dx];
            #pragma unroll
            for (int p = 0; p < 4; ++p)
              acc[o][p] = fmaf(w, pin[dy][dx + p], acc[o][p]);
          }
    }
    __syncthreads();
  }

  if (a.mode == 0) {
    float* outp = ((lvl == 0) ? a.out0 : ((lvl == 1) ? a.out1 : a.out2)) + (size_t)img * 256 * HW;
    float* hwcb = (lvl == 0) ? a.hwc0 : ((lvl == 1) ? a.hwc1 : a.hwc2);
    float* hwcp = hwcb ? (hwcb + (size_t)img * HW * 256) : nullptr;
    #pragma unroll
    for (int o = 0; o < 4; ++o) {
      int oc = ocbase + oc_t * 4 + o;
      float iv = a.inv[oc], bb = a.beta[oc];
      #pragma unroll
      for (int p = 0; p < 4; ++p) {
        int y = ty0 + rr, x = tx0 + cc + p;
        float v = acc[o][p] * iv + bb;
        v = (v >= 0.f) ? v : 0.01f * v;
        outp[(size_t)oc * HW + y * H + x] = v;
        if (hwcp) hwcp[((size_t)y * H + x) * 256 + oc] = v;
      }
    }
  } else {
    int abase = (lvl == 0) ? 0 : ((lvl == 1) ? 12288 : 15360);
    #pragma unroll
    for (int p = 0; p < 4; ++p) {
      int y = ty0 + rr, x = tx0 + cc + p;
      int gi = img * 16128 + abase + (y * H + x) * 3;
      #pragma unroll
      for (int o = 0; o < 4; ++o) {
        int oc = oc_t * 4 + o;
        float v = acc[o][p];
        if (oc < 3) a.logits[gi + oc] = v;
        else if (oc < 15) {
          int r2 = oc - 3;
          a.tvals[(size_t)(gi + (r2 >> 2)) * 4 + (r2 & 3)] = v;
        }
      }
    }
  }
}

// ---------------- decode helper ----------------
__device__ __forceinline__ void decode_one(const float* __restrict__ anch,
                                           const float* __restrict__ tv, int i,
                                           float& x1, float& y1, float& x2, float& y2)
{
  float t0 = tv[i * 4 + 0], t1 = tv[i * 4 + 1], t2 = tv[i * 4 + 2], t3 = tv[i * 4 + 3];
  float a0 = anch[i * 4 + 0], a1 = anch[i * 4 + 1], a2 = anch[i * 4 + 2], a3 = anch[i * 4 + 3];
  float aw = a2 - a0, ah = a3 - a1;
  float xx = a0 + t0 * aw;
  float yy = a1 + t1 * ah;
  float bw = aw * expf(t2);
  float bh = ah * expf(t3);
  x1 = fminf(fmaxf(xx, 0.f), 512.f);
  y1 = fminf(fmaxf(yy, 0.f), 512.f);
  x2 = fminf(fmaxf(xx + bw, 0.f), 512.f);
  y2 = fminf(fmaxf(yy + bh, 0.f), 512.f);
}

// ---------------- postproc: score/valid -> top256 -> NMS -> order -> dets/mask/coords ----------------
__global__ __launch_bounds__(256) void postproc_kernel(
    const float* __restrict__ logits, const float* __restrict__ tvals,
    const float* __restrict__ anch0, const float* __restrict__ anch1, const float* __restrict__ anch2,
    unsigned int* __restrict__ skey, float* __restrict__ dout, int* __restrict__ coords)
{
  int lvl = blockIdx.x, img = blockIdx.y;
  int N = (lvl == 0) ? 12288 : ((lvl == 1) ? 3072 : 768);
  int stride = (lvl == 0) ? 8 : ((lvl == 1) ? 16 : 32);
  int abase = (lvl == 0) ? 0 : ((lvl == 1) ? 12288 : 15360);
  const float* anch = (lvl == 0) ? anch0 : ((lvl == 1) ? anch1 : anch2);
  const float* lg = logits + img * 16128 + abase;
  const float* tv = tvals + (size_t)(img * 16128 + abase) * 4;
  unsigned int* sk = skey + img * 16128 + abase;
  int tx = threadIdx.x;
  float minsz = 2.0f * (float)stride;

  // phase A: keys
  for (int i = tx; i < N; i += 256) {
    float lv = lg[i];
    float sc = 1.f / (1.f + expf(-lv));
    float x1, y1, x2, y2;
    decode_one(anch, tv, i, x1, y1, x2, y2);
    bool valid = (sc > 0.5f) && ((x2 - x1) >= minsz) && ((y2 - y1) >= minsz);
    sk[i] = valid ? __float_as_uint(sc) : 0u;
  }
  __syncthreads();

  // radix-select the 256th-largest score key (3 passes: 11/11/10 bits)
  __shared__ unsigned int hist[2048];
  __shared__ int sh_c, sh_needed;
  unsigned int prefix = 0u, pmask = 0u;
  int needed = 256, V = 0;
  for (int pass = 0; pass < 3; ++pass) {
    int shift = (pass == 0) ? 21 : ((pass == 1) ? 10 : 0);
    unsigned int cmask = (pass == 2) ? 1023u : 2047u;
    for (int i = tx; i < 2048; i += 256) hist[i] = 0u;
    __syncthreads();
    for (int i = tx; i < N; i += 256) {
      unsigned int v = sk[i];
      if (v != 0u && (v & pmask) == prefix)
        atomicAdd(&hist[(v >> shift) & cmask], 1u);
    }
    __syncthreads();
    for (int off = 1; off < 2048; off <<= 1) {
      unsigned int tmp[8];
      #pragma unroll
      for (int q = 0; q < 8; ++q) { int i = tx + q * 256; tmp[q] = (i + off < 2048) ? hist[i + off] : 0u; }
      __syncthreads();
      #pragma unroll
      for (int q = 0; q < 8; ++q) { int i = tx + q * 256; hist[i] += tmp[q]; }
      __syncthreads();
    }
    if (pass == 0) { V = (int)hist[0]; if (V < needed) needed = V; }
    if (needed > 0) {
      for (int i = tx; i < 2048; i += 256) {
        int Si = (int)hist[i];
        int Sn = (i + 1 < 2048) ? (int)hist[i + 1] : 0;
        if (Si >= needed && Sn < needed) { sh_c = i; sh_needed = needed - Sn; }
      }
    }
    __syncthreads();
    if (needed > 0) {
      prefix |= ((unsigned)sh_c) << shift;
      pmask |= cmask << shift;
      needed = sh_needed;
    }
    __syncthreads();
  }
  unsigned int Sstar = (V > 0) ? prefix : 0xFFFFFFFFu;

  // collect candidates >= Sstar, sort desc by (score_bits, ~idx)
  __shared__ unsigned long long slist[1024];
  __shared__ int scnt;
  if (tx == 0) scnt = 0;
  for (int i = tx; i < 1024; i += 256) slist[i] = 0ull;
  __syncthreads();
  for (int i = tx; i < N; i += 256) {
    unsigned int v = sk[i];
    if (v != 0u && v >= Sstar) {
      int p = atomicAdd(&scnt, 1);
      if (p < 1024)
        slist[p] = ((unsigned long long)v << 32) | (unsigned long long)(0xFFFFFFFFu - (unsigned)i);
    }
  }
  __syncthreads();
  for (int k = 2; k <= 1024; k <<= 1) {
    for (int j = k >> 1; j > 0; j >>= 1) {
      for (int i2 = tx; i2 < 1024; i2 += 256) {
        int pp = i2 ^ j;
        if (pp > i2) {
          unsigned long long va = slist[i2], vb = slist[pp];
          bool descPair = ((i2 & k) == 0);
          if (descPair ? (va < vb) : (va > vb)) { slist[i2] = vb; slist[pp] = va; }
        }
      }
      __syncthreads();
    }
  }

  // decode 256 slots
  __shared__ float bx0[256], bx1[256], bx2[256], bx3[256], bsc[256], bar[256];
  __shared__ int bkeep[256];
  {
    unsigned long long key = slist[tx];
    float x1 = 0.f, y1 = 0.f, x2 = 0.f, y2 = 0.f, sc = 0.f;
    if (key != 0ull) {
      sc = __uint_as_float((unsigned int)(key >> 32));
      int idx = (int)(0xFFFFFFFFu - (unsigned int)(key & 0xFFFFFFFFull));
      decode_one(anch, tv, idx, x1, y1, x2, y2);
    }
    bx0[tx] = x1; bx1[tx] = y1; bx2[tx] = x2; bx3[tx] = y2;
    bsc[tx] = sc;
    bar[tx] = (x2 - x1 + 1.f) * (y2 - y1 + 1.f);
    bkeep[tx] = (sc > 0.5f) ? 1 : 0;
  }
  __syncthreads();

  // greedy sequential NMS
  for (int i = 0; i < 255; ++i) {
    if (bkeep[i]) {
      float xi1 = bx0[i], yi1 = bx1[i], xi2 = bx2[i], yi2 = bx3[i], ai = bar[i];
      if (tx > i && bkeep[tx]) {
        float xx1 = fmaxf(xi1, bx0[tx]);
        float yy1 = fmaxf(yi1, bx1[tx]);
        float xx2 = fminf(xi2, bx2[tx]);
        float yy2 = fminf(yi2, bx3[tx]);
        float w = fmaxf(0.f, xx2 - xx1 + 1.f);
        float h = fmaxf(0.f, yy2 - yy1 + 1.f);
        float inter = w * h;
        float ovr = inter / (ai + bar[tx] - inter);
        if (ovr > 0.3f) bkeep[tx] = 0;
      }
    }
    __syncthreads();
  }

  // stable order: kept first (rank order), take 32
  __shared__ int sel[32];
  if (tx == 0) {
    int s = 0;
    for (int r = 0; r < 256 && s < 32; ++r) if (bkeep[r]) sel[s++] = r;
    for (int r = 0; r < 256 && s < 32; ++r) if (!bkeep[r]) sel[s++] = r;
  }
  __syncthreads();
  if (tx < 32) {
    int r = sel[tx];
    int m = bkeep[r];
    int ob = (img * 3 + lvl) * 32 + tx;
    float d0 = 0.f, d1 = 0.f, d2 = 0.f, d3 = 0.f, d4 = 0.f;
    int c0 = 0, c1 = 0, c2 = 2, c3 = 2;
    if (m) {
      d0 = bx0[r]; d1 = bx1[r]; d2 = bx2[r]; d3 = bx3[r]; d4 = bsc[r];
      c0 = ((int)d0) / stride; c1 = ((int)d1) / stride;
      c2 = ((int)d2) / stride; c3 = ((int)d3) / stride;
    }
    dout[ob * 5 + 0] = d0; dout[ob * 5 + 1] = d1; dout[ob * 5 + 2] = d2;
    dout[ob * 5 + 3] = d3; dout[ob * 5 + 4] = d4;
    dout[960 + ob] = m ? 1.f : 0.f;
    coords[ob * 5 + 0] = c0; coords[ob * 5 + 1] = c1;
    coords[ob * 5 + 2] = c2; coords[ob * 5 + 3] = c3;
    coords[ob * 5 + 4] = m;
  }
}

// ---------------- ROI adaptive 7x7 maxpool (reads HWC features) ----------------
__global__ __launch_bounds__(256) void roipool_kernel(
    const float* __restrict__ fh0, const float* __restrict__ fh1, const float* __restrict__ fh2,
    const int* __restrict__ coords, float* __restrict__ dout)
{
  int slot = blockIdx.x, lvl = blockIdx.y, img = blockIdx.z;
  int ob = (img * 3 + lvl) * 32 + slot;
  int c = threadIdx.x;
  const int* cw = coords + ob * 5;
  float* outp = dout + 1152 + (size_t)ob * 256 * 49 + (size_t)c * 49;
  int m = cw[4];
  if (!m) {
    #pragma unroll
    for (int i = 0; i < 49; ++i) outp[i] = 0.f;
    return;
  }
  int H = (lvl == 0) ? 64 : ((lvl == 1) ? 32 : 16);
  const float* f = ((lvl == 0) ? fh0 : ((lvl == 1) ? fh1 : fh2)) + (size_t)img * H * H * 256;
  int lox = cw[0], loy = cw[1], hix = cw[2], hiy = cw[3];
  int Lx = hix - lox, Ly = hiy - loy;
  for (int yi = 0; yi < 7; ++yi) {
    int ys = loy + (yi * Ly) / 7;
    int ye = loy + ((yi + 1) * Ly + 6) / 7;
    for (int xi = 0; xi < 7; ++xi) {
      int xs = lox + (xi * Lx) / 7;
      int xe = lox + ((xi + 1) * Lx + 6) / 7;
      float mx = -3.402823466e+38f;
      for (int y = ys; y < ye; ++y)
        for (int x = xs; x < xe; ++x)
          mx = fmaxf(mx, f[((size_t)y * H + x) * 256 + c]);
      outp[yi * 7 + xi] = mx;
    }
  }
}

// ---------------- host ----------------
extern "C" void kernel_launch(void* const* d_in, const int* in_sizes, int n_in,
                              void* d_out, int out_size, void* d_ws, size_t ws_size,
                              hipStream_t stream)
{
  (void)in_sizes; (void)n_in; (void)out_size; (void)ws_size;
  float* ws = (float*)d_ws;
  const float* layer2 = (const float*)d_in[0];
  const float* layer3 = (const float*)d_in[1];
  const float* layer4 = (const float*)d_in[2];
  const float* anch2  = (const float*)d_in[3];
  const float* anch3  = (const float*)d_in[4];
  const float* anch4  = (const float*)d_in[5];
  const float* hw1 = (const float*)d_in[6];
  const float* hg1 = (const float*)d_in[7];
  const float* hb1 = (const float*)d_in[8];
  const float* hm1 = (const float*)d_in[9];
  const float* hv1 = (const float*)d_in[10];
  const float* hw2 = (const float*)d_in[11];
  const float* hg2 = (const float*)d_in[12];
  const float* hb2 = (const float*)d_in[13];
  const float* hm2 = (const float*)d_in[14];
  const float* hv2 = (const float*)d_in[15];
  const float* clsw = (const float*)d_in[16];
  const float* locw = (const float*)d_in[17];
  float* dout = (float*)d_out;

  float* l2   = ws + WS_OFF_L2;
  float* l3   = ws + WS_OFF_L3;
  float* h1_2 = ws + WS_OFF_H1_2;
  float* h1_3 = ws + WS_OFF_H1_3;
  float* h1_4 = ws + WS_OFF_H1_4;
  float* f2   = ws + WS_OFF_L2;   // alias: l2 dead after conv1
  float* f3   = ws + WS_OFF_L3;   // alias
  float* f4   = ws + WS_OFF_F4;
  float* fh2  = ws + WS_OFF_FH2;
  float* fh3  = ws + WS_OFF_FH3;
  float* fh4  = ws + WS_OFF_FH4;
  float* rpnw = ws + WS_OFF_RPNW;
  float* inv1 = ws + WS_OFF_INV1;
  float* beta1= ws + WS_OFF_BETA1;
  float* inv2 = ws + WS_OFF_INV2;
  float* beta2= ws + WS_OFF_BETA2;
  float* logits = ws + WS_OFF_LOGITS;
  float* tvals  = ws + WS_OFF_TVALS;
  unsigned int* skey = (unsigned int*)(ws + WS_OFF_SKEY);
  int* coords = (int*)(ws + WS_OFF_COORDS);

  prep_kernel<<<64, 256, 0, stream>>>(hg1, hb1, hm1, hv1, hg2, hb2, hm2, hv2, clsw, locw, ws);
  merge_up2_kernel<<<524288 / 256, 256, 0, stream>>>(layer3, layer4, l3, 32, 524288);
  merge_up2_kernel<<<2097152 / 256, 256, 0, stream>>>(layer2, l3, l2, 64, 2097152);

  ConvArgs c1;
  c1.in0 = l2; c1.in1 = l3; c1.in2 = layer4;
  c1.out0 = h1_2; c1.out1 = h1_3; c1.out2 = h1_4;
  c1.hwc0 = nullptr; c1.hwc1 = nullptr; c1.hwc2 = nullptr;
  c1.W = hw1; c1.inv = inv1; c1.beta = beta1;
  c1.logits = nullptr; c1.tvals = nullptr; c1.mode = 0;
  conv3x3_kernel<<<dim3(84, 4, 2), 256, 0, stream>>>(c1);

  ConvArgs c2;
  c2.in0 = h1_2; c2.in1 = h1_3; c2.in2 = h1_4;
  c2.out0 = f2; c2.out1 = f3; c2.out2 = f4;
  c2.hwc0 = fh2; c2.hwc1 = fh3; c2.hwc2 = fh4;
  c2.W = hw2; c2.inv = inv2; c2.beta = beta2;
  c2.logits = nullptr; c2.tvals = nullptr; c2.mode = 0;
  conv3x3_kernel<<<dim3(84, 4, 2), 256, 0, stream>>>(c2);

  ConvArgs cr;
  cr.in0 = f2; cr.in1 = f3; cr.in2 = f4;
  cr.out0 = nullptr; cr.out1 = nullptr; cr.out2 = nullptr;
  cr.hwc0 = nullptr; cr.hwc1 = nullptr; cr.hwc2 = nullptr;
  cr.W = rpnw; cr.inv = nullptr; cr.beta = nullptr;
  cr.logits = logits; cr.tvals = tvals; cr.mode = 1;
  conv3x3_kernel<<<dim3(84, 1, 2), 256, 0, stream>>>(cr);

  postproc_kernel<<<dim3(3, 2), 256, 0, stream>>>(logits, tvals, anch2, anch3, anch4, skey, dout, coords);
  roipool_kernel<<<dim3(32, 3, 2), 256, 0, stream>>>(fh2, fh3, fh4, coords, dout);
}

// Round 2
// 657.621 us; speedup vs baseline: 1.7571x; 1.7571x over previous
//
#include <hip/hip_runtime.h>
#include <math.h>

typedef __attribute__((ext_vector_type(8))) short short8;
typedef __attribute__((ext_vector_type(16))) float f32x16;
typedef __attribute__((ext_vector_type(4))) float float4v;

// ---------------- bf16 helpers ----------------
__device__ __forceinline__ unsigned short f2bf(float f) {
  unsigned u = __float_as_uint(f);
  unsigned r = ((u >> 16) & 1u) + 0x7FFFu;
  return (unsigned short)((u + r) >> 16);
}
__device__ __forceinline__ float bf2f(unsigned short h) {
  return __uint_as_float(((unsigned)h) << 16);
}
__device__ __forceinline__ void split3(float v, short& h, short& m, short& l) {
  unsigned short hh = f2bf(v);
  float r1 = v - bf2f(hh);
  unsigned short mm = f2bf(r1);
  float r2 = r1 - bf2f(mm);
  unsigned short ll = f2bf(r2);
  h = (short)hh; m = (short)mm; l = (short)ll;
}
__device__ __forceinline__ short8 zero8() {
  short8 z;
  #pragma unroll
  for (int j = 0; j < 8; ++j) z[j] = 0;
  return z;
}

// ---------------- workspace layout (byte offsets) ----------------
#define OFF_W1H  0UL
#define OFF_W1M  1179648UL
#define OFF_W1L  2359296UL
#define OFF_W2H  3538944UL
#define OFF_W2M  4718592UL
#define OFF_W2L  5898240UL
#define OFF_WRH  7077888UL
#define OFF_WRM  7372800UL
#define OFF_WRL  7667712UL
#define OFF_I0   7962624UL    // 2*4096*256 f32 = 8388608 B  (aliased as fh0 after conv1)
#define OFF_I1   16351232UL   // 2*1024*256 f32 = 2097152 B  (fh1)
#define OFF_I2   18448384UL   // 2*256*256 f32 = 524288 B    (fh2)
#define OFF_L3F  18972672UL   // 2097152 B
#define OFF_H0   21069824UL   // 8388608
#define OFF_H1   29458432UL   // 2097152
#define OFF_H2   31555584UL   // 524288
#define OFF_INV1 32079872UL
#define OFF_BETA1 32080896UL
#define OFF_INV2 32081920UL
#define OFF_BETA2 32082944UL
#define OFF_LOGITS 32083968UL // 2*16128*4 = 129024
#define OFF_TVALS  32212992UL // 516096
#define OFF_SKEY   32729088UL // 129024
#define OFF_COORDS 32858112UL // 3840
// total ~32.9 MB

// out layout: dets[2][3][32][5] @0 (960) | mask[2][3][32] @960 (192) | rois @1152

// ---------------- prep: BN fold ----------------
__global__ __launch_bounds__(256) void prep_bn_kernel(
    const float* __restrict__ hg1, const float* __restrict__ hb1,
    const float* __restrict__ hm1, const float* __restrict__ hv1,
    const float* __restrict__ hg2, const float* __restrict__ hb2,
    const float* __restrict__ hm2, const float* __restrict__ hv2,
    char* __restrict__ ws)
{
  int t = threadIdx.x;
  float* inv1 = (float*)(ws + OFF_INV1);
  float* beta1 = (float*)(ws + OFF_BETA1);
  float* inv2 = (float*)(ws + OFF_INV2);
  float* beta2 = (float*)(ws + OFF_BETA2);
  float i1 = (float)((double)hg1[t] / sqrt((double)hv1[t] + 1e-5));
  inv1[t] = i1;
  beta1[t] = hb1[t] - hm1[t] * i1;
  float i2 = (float)((double)hg2[t] / sqrt((double)hv2[t] + 1e-5));
  inv2[t] = i2;
  beta2[t] = hb2[t] - hm2[t] * i2;
}

// ---------------- prep: weight split into [dydx][oc][ic] bf16 h/m/l ----------------
#define L1SZ 589824   // 9*256*256
#define RPNSZ 147456  // 9*64*256
__global__ __launch_bounds__(256) void prep_w_kernel(
    const float* __restrict__ hw1, const float* __restrict__ hw2,
    const float* __restrict__ clsw, const float* __restrict__ locw,
    char* __restrict__ ws)
{
  short* w1h = (short*)(ws + OFF_W1H);
  short* w1m = (short*)(ws + OFF_W1M);
  short* w1l = (short*)(ws + OFF_W1L);
  short* w2h = (short*)(ws + OFF_W2H);
  short* w2m = (short*)(ws + OFF_W2M);
  short* w2l = (short*)(ws + OFF_W2L);
  short* wrh = (short*)(ws + OFF_WRH);
  short* wrm = (short*)(ws + OFF_WRM);
  short* wrl = (short*)(ws + OFF_WRL);
  const int TOT = 2 * L1SZ + RPNSZ;
  for (int e = blockIdx.x * 256 + threadIdx.x; e < TOT; e += gridDim.x * 256) {
    float val; short *dh, *dm, *dl; int di;
    if (e < L1SZ) {
      int dydx = e >> 16, oc = (e >> 8) & 255, ic = e & 255;
      val = hw1[(size_t)(oc * 256 + ic) * 9 + dydx];
      dh = w1h; dm = w1m; dl = w1l; di = e;
    } else if (e < 2 * L1SZ) {
      int e2 = e - L1SZ;
      int dydx = e2 >> 16, oc = (e2 >> 8) & 255, ic = e2 & 255;
      val = hw2[(size_t)(oc * 256 + ic) * 9 + dydx];
      dh = w2h; dm = w2m; dl = w2l; di = e2;
    } else {
      int e3 = e - 2 * L1SZ;
      int dydx = e3 >> 14, oc = (e3 >> 8) & 63, ic = e3 & 255;
      if (oc < 3) val = clsw[(size_t)(oc * 256 + ic) * 9 + dydx];
      else if (oc < 15) val = locw[(size_t)((oc - 3) * 256 + ic) * 9 + dydx];
      else val = 0.f;
      dh = wrh; dm = wrm; dl = wrl; di = e3;
    }
    short h, m, l;
    split3(val, h, m, l);
    dh[di] = h; dm[di] = m; dl[di] = l;
  }
}

// ---------------- fuse: out_hwc = a_chw + upsample2x(b_chw); optional f32 CHW copy ----------------
__global__ __launch_bounds__(256) void fuse_kernel(
    const float* __restrict__ a, const float* __restrict__ bUp,
    float* __restrict__ f32chw, float* __restrict__ ohwc,
    int H, int logW)
{
  __shared__ float T[32][65];
  int HW = H * H;
  int img = blockIdx.y;
  const float* ap = a + (size_t)img * 256 * HW;
  const float* bp = bUp ? (bUp + (size_t)img * 256 * (HW >> 2)) : nullptr;
  float* fp = f32chw ? (f32chw + (size_t)img * 256 * HW) : nullptr;
  float* op = ohwc + (size_t)img * HW * 256;
  int p0 = blockIdx.x * 64;
  int tid = threadIdx.x;
  int px = tid & 63, cg = tid >> 6;
  int gp = p0 + px;
  int y = gp >> logW, x = gp & (H - 1);
  int px2 = tid >> 2, q = tid & 3;
  for (int c0 = 0; c0 < 256; c0 += 32) {
    #pragma unroll
    for (int cc = 0; cc < 8; ++cc) {
      int c = c0 + cg * 8 + cc;
      float v = ap[(size_t)c * HW + gp];
      if (bp) v += bp[(size_t)c * (HW >> 2) + (y >> 1) * (H >> 1) + (x >> 1)];
      if (fp) fp[(size_t)c * HW + gp] = v;
      T[cg * 8 + cc][px] = v;
    }
    __syncthreads();
    {
      size_t oa = (size_t)(p0 + px2) * 256 + c0 + q * 8;
      float4v v0, v1;
      #pragma unroll
      for (int j = 0; j < 4; ++j) v0[j] = T[q * 8 + j][px2];
      #pragma unroll
      for (int j = 0; j < 4; ++j) v1[j] = T[q * 8 + 4 + j][px2];
      *(float4v*)&op[oa] = v0;
      *(float4v*)&op[oa + 4] = v1;
    }
    __syncthreads();
  }
}

// ---------------- MFMA implicit-GEMM 3x3 conv ----------------
struct CArgs {
  const float* in0; const float* in1; const float* in2;   // f32 HWC per level
  const short* wh; const short* wm; const short* wl;      // [9][ocw][256]
  float* out0; float* out1; float* out2;                  // f32 HWC outs (modes 0,1)
  const float* inv; const float* beta;                    // BN folded
  float* logits; float* tvals;                            // mode 2
  int ocw; int mode;
};

__global__ __launch_bounds__(256) void conv_mfma_kernel(CArgs a)
{
  __shared__ short Ph[100 * 40], Pm[100 * 40], Pl[100 * 40];      // 24000 B
  __shared__ short WhS[2 * 64 * 40], WmS[2 * 64 * 40], WlS[2 * 64 * 40]; // 30720 B

  int bt = blockIdx.x;
  int lvl, tile;
  if (bt < 64) { lvl = 0; tile = bt; }
  else if (bt < 80) { lvl = 1; tile = bt - 64; }
  else { lvl = 2; tile = bt - 80; }
  int H = (lvl == 0) ? 64 : ((lvl == 1) ? 32 : 16);
  int HW = H * H;
  int tpr = H >> 3;
  int ty0 = (tile / tpr) * 8, tx0 = (tile % tpr) * 8;
  int img = blockIdx.z;
  int ocbase = blockIdx.y * 64;
  const float* inp = ((lvl == 0) ? a.in0 : ((lvl == 1) ? a.in1 : a.in2)) + (size_t)img * HW * 256;

  int tid = threadIdx.x;
  int l = tid & 63, w = tid >> 6;
  int wr = w >> 1, wc = w & 1;
  int row = l & 31, khalf = l >> 5;
  int m0 = wr * 32 + row;
  int my = m0 >> 3, mx = m0 & 7;
  int aBase = (my * 10 + mx) * 40 + khalf * 8;   // short offset, + dydx*... added later
  int bBase = (wc * 32 + row) * 40 + khalf * 8;

  f32x16 acc;
  #pragma unroll
  for (int j = 0; j < 16; ++j) acc[j] = 0.f;

  for (int icb = 0; icb < 8; ++icb) {
    // ---- stage input patch 10x10 x 32ic, split to 3x bf16 ----
    for (int u = tid; u < 400; u += 256) {
      int pxl = u >> 2, icq = u & 3;
      int py = pxl / 10, pxx = pxl - py * 10;
      int gy = ty0 + py - 1, gx = tx0 + pxx - 1;
      int lo = pxl * 40 + icq * 8;
      short8 sh, sm, sl;
      if ((unsigned)gy < (unsigned)H && (unsigned)gx < (unsigned)H) {
        const float* gptr = inp + (size_t)(gy * H + gx) * 256 + icb * 32 + icq * 8;
        #pragma unroll
        for (int j = 0; j < 8; ++j) {
          short hh, mm, ll;
          split3(gptr[j], hh, mm, ll);
          sh[j] = hh; sm[j] = mm; sl[j] = ll;
        }
      } else { sh = zero8(); sm = zero8(); sl = zero8(); }
      *(short8*)&Ph[lo] = sh;
      *(short8*)&Pm[lo] = sm;
      *(short8*)&Pl[lo] = sl;
    }
    __syncthreads();

    for (int g = 0; g < 5; ++g) {
      int dcount = (g == 4) ? 1 : 2;
      // ---- stage weights: dcount dydx slices of [64 oc][32 ic] x3 ----
      {
        int ocr = tid >> 2, icq = tid & 3;
        for (int d = 0; d < dcount; ++d) {
          int dydx = g * 2 + d;
          size_t ga = ((size_t)dydx * a.ocw + ocbase + ocr) * 256 + icb * 32 + icq * 8;
          int lo = (d * 64 + ocr) * 40 + icq * 8;
          *(short8*)&WhS[lo] = *(const short8*)&a.wh[ga];
          *(short8*)&WmS[lo] = *(const short8*)&a.wm[ga];
          *(short8*)&WlS[lo] = *(const short8*)&a.wl[ga];
        }
      }
      __syncthreads();
      // ---- MFMA ----
      for (int d = 0; d < dcount; ++d) {
        int dydx = g * 2 + d;
        int dy = dydx / 3, dx = dydx - dy * 3;
        int pA = aBase + (dy * 10 + dx) * 40;
        int pB = bBase + d * 64 * 40;
        #pragma unroll
        for (int k2 = 0; k2 < 2; ++k2) {
          int oA = pA + k2 * 16, oB = pB + k2 * 16;
          short8 ah = *(const short8*)&Ph[oA];
          short8 am = *(const short8*)&Pm[oA];
          short8 al = *(const short8*)&Pl[oA];
          short8 bh = *(const short8*)&WhS[oB];
          short8 bm = *(const short8*)&WmS[oB];
          short8 bl = *(const short8*)&WlS[oB];
          acc = __builtin_amdgcn_mfma_f32_32x32x16_bf16(ah, bh, acc, 0, 0, 0);
          acc = __builtin_amdgcn_mfma_f32_32x32x16_bf16(ah, bm, acc, 0, 0, 0);
          acc = __builtin_amdgcn_mfma_f32_32x32x16_bf16(am, bh, acc, 0, 0, 0);
          acc = __builtin_amdgcn_mfma_f32_32x32x16_bf16(ah, bl, acc, 0, 0, 0);
          acc = __builtin_amdgcn_mfma_f32_32x32x16_bf16(am, bm, acc, 0, 0, 0);
          acc = __builtin_amdgcn_mfma_f32_32x32x16_bf16(al, bh, acc, 0, 0, 0);
        }
      }
      __syncthreads();
    }
  }

  // ---- epilogue ----
  int oc = ocbase + wc * 32 + row;
  if (a.mode != 2) {
    float iv = a.inv[oc], bb = a.beta[oc];
    float* outp = ((lvl == 0) ? a.out0 : ((lvl == 1) ? a.out1 : a.out2)) + (size_t)img * HW * 256;
    #pragma unroll
    for (int r = 0; r < 16; ++r) {
      int ml = (r & 3) + 8 * (r >> 2) + 4 * khalf;
      int m = wr * 32 + ml;
      int y = ty0 + (m >> 3), x = tx0 + (m & 7);
      float v = acc[r] * iv + bb;
      v = (v >= 0.f) ? v : 0.01f * v;
      outp[(size_t)(y * H + x) * 256 + oc] = v;
    }
  } else {
    if (oc < 15) {
      int abase = (lvl == 0) ? 0 : ((lvl == 1) ? 12288 : 15360);
      #pragma unroll
      for (int r = 0; r < 16; ++r) {
        int ml = (r & 3) + 8 * (r >> 2) + 4 * khalf;
        int m = wr * 32 + ml;
        int y = ty0 + (m >> 3), x = tx0 + (m & 7);
        int gi = img * 16128 + abase + (y * H + x) * 3;
        float v = acc[r];
        if (oc < 3) a.logits[gi + oc] = v;
        else { int r2 = oc - 3; a.tvals[(size_t)(gi + (r2 >> 2)) * 4 + (r2 & 3)] = v; }
      }
    }
  }
}

// ---------------- decode helper ----------------
__device__ __forceinline__ void decode_one(const float* __restrict__ anch,
                                           const float* __restrict__ tv, int i,
                                           float& x1, float& y1, float& x2, float& y2)
{
  float t0 = tv[i * 4 + 0], t1 = tv[i * 4 + 1], t2 = tv[i * 4 + 2], t3 = tv[i * 4 + 3];
  float a0 = anch[i * 4 + 0], a1 = anch[i * 4 + 1], a2 = anch[i * 4 + 2], a3 = anch[i * 4 + 3];
  float aw = a2 - a0, ah = a3 - a1;
  float xx = a0 + t0 * aw;
  float yy = a1 + t1 * ah;
  float bw = aw * expf(t2);
  float bh = ah * expf(t3);
  x1 = fminf(fmaxf(xx, 0.f), 512.f);
  y1 = fminf(fmaxf(yy, 0.f), 512.f);
  x2 = fminf(fmaxf(xx + bw, 0.f), 512.f);
  y2 = fminf(fmaxf(yy + bh, 0.f), 512.f);
}

// ---------------- postproc (unchanged from round 1) ----------------
__global__ __launch_bounds__(256) void postproc_kernel(
    const float* __restrict__ logits, const float* __restrict__ tvals,
    const float* __restrict__ anch0, const float* __restrict__ anch1, const float* __restrict__ anch2,
    unsigned int* __restrict__ skey, float* __restrict__ dout, int* __restrict__ coords)
{
  int lvl = blockIdx.x, img = blockIdx.y;
  int N = (lvl == 0) ? 12288 : ((lvl == 1) ? 3072 : 768);
  int stride = (lvl == 0) ? 8 : ((lvl == 1) ? 16 : 32);
  int abase = (lvl == 0) ? 0 : ((lvl == 1) ? 12288 : 15360);
  const float* anch = (lvl == 0) ? anch0 : ((lvl == 1) ? anch1 : anch2);
  const float* lg = logits + img * 16128 + abase;
  const float* tv = tvals + (size_t)(img * 16128 + abase) * 4;
  unsigned int* sk = skey + img * 16128 + abase;
  int tx = threadIdx.x;
  float minsz = 2.0f * (float)stride;

  for (int i = tx; i < N; i += 256) {
    float lv = lg[i];
    float sc = 1.f / (1.f + expf(-lv));
    float x1, y1, x2, y2;
    decode_one(anch, tv, i, x1, y1, x2, y2);
    bool valid = (sc > 0.5f) && ((x2 - x1) >= minsz) && ((y2 - y1) >= minsz);
    sk[i] = valid ? __float_as_uint(sc) : 0u;
  }
  __syncthreads();

  __shared__ unsigned int hist[2048];
  __shared__ int sh_c, sh_needed;
  unsigned int prefix = 0u, pmask = 0u;
  int needed = 256, V = 0;
  for (int pass = 0; pass < 3; ++pass) {
    int shift = (pass == 0) ? 21 : ((pass == 1) ? 10 : 0);
    unsigned int cmask = (pass == 2) ? 1023u : 2047u;
    for (int i = tx; i < 2048; i += 256) hist[i] = 0u;
    __syncthreads();
    for (int i = tx; i < N; i += 256) {
      unsigned int v = sk[i];
      if (v != 0u && (v & pmask) == prefix)
        atomicAdd(&hist[(v >> shift) & cmask], 1u);
    }
    __syncthreads();
    for (int off = 1; off < 2048; off <<= 1) {
      unsigned int tmp[8];
      #pragma unroll
      for (int q = 0; q < 8; ++q) { int i = tx + q * 256; tmp[q] = (i + off < 2048) ? hist[i + off] : 0u; }
      __syncthreads();
      #pragma unroll
      for (int q = 0; q < 8; ++q) { int i = tx + q * 256; hist[i] += tmp[q]; }
      __syncthreads();
    }
    if (pass == 0) { V = (int)hist[0]; if (V < needed) needed = V; }
    if (needed > 0) {
      for (int i = tx; i < 2048; i += 256) {
        int Si = (int)hist[i];
        int Sn = (i + 1 < 2048) ? (int)hist[i + 1] : 0;
        if (Si >= needed && Sn < needed) { sh_c = i; sh_needed = needed - Sn; }
      }
    }
    __syncthreads();
    if (needed > 0) {
      prefix |= ((unsigned)sh_c) << shift;
      pmask |= cmask << shift;
      needed = sh_needed;
    }
    __syncthreads();
  }
  unsigned int Sstar = (V > 0) ? prefix : 0xFFFFFFFFu;

  __shared__ unsigned long long slist[1024];
  __shared__ int scnt;
  if (tx == 0) scnt = 0;
  for (int i = tx; i < 1024; i += 256) slist[i] = 0ull;
  __syncthreads();
  for (int i = tx; i < N; i += 256) {
    unsigned int v = sk[i];
    if (v != 0u && v >= Sstar) {
      int p = atomicAdd(&scnt, 1);
      if (p < 1024)
        slist[p] = ((unsigned long long)v << 32) | (unsigned long long)(0xFFFFFFFFu - (unsigned)i);
    }
  }
  __syncthreads();
  for (int k = 2; k <= 1024; k <<= 1) {
    for (int j = k >> 1; j > 0; j >>= 1) {
      for (int i2 = tx; i2 < 1024; i2 += 256) {
        int pp = i2 ^ j;
        if (pp > i2) {
          unsigned long long va = slist[i2], vb = slist[pp];
          bool descPair = ((i2 & k) == 0);
          if (descPair ? (va < vb) : (va > vb)) { slist[i2] = vb; slist[pp] = va; }
        }
      }
      __syncthreads();
    }
  }

  __shared__ float bx0[256], bx1[256], bx2[256], bx3[256], bsc[256], bar[256];
  __shared__ int bkeep[256];
  {
    unsigned long long key = slist[tx];
    float x1 = 0.f, y1 = 0.f, x2 = 0.f, y2 = 0.f, sc = 0.f;
    if (key != 0ull) {
      sc = __uint_as_float((unsigned int)(key >> 32));
      int idx = (int)(0xFFFFFFFFu - (unsigned int)(key & 0xFFFFFFFFull));
      decode_one(anch, tv, idx, x1, y1, x2, y2);
    }
    bx0[tx] = x1; bx1[tx] = y1; bx2[tx] = x2; bx3[tx] = y2;
    bsc[tx] = sc;
    bar[tx] = (x2 - x1 + 1.f) * (y2 - y1 + 1.f);
    bkeep[tx] = (sc > 0.5f) ? 1 : 0;
  }
  __syncthreads();

  for (int i = 0; i < 255; ++i) {
    if (bkeep[i]) {
      float xi1 = bx0[i], yi1 = bx1[i], xi2 = bx2[i], yi2 = bx3[i], ai = bar[i];
      if (tx > i && bkeep[tx]) {
        float xx1 = fmaxf(xi1, bx0[tx]);
        float yy1 = fmaxf(yi1, bx1[tx]);
        float xx2 = fminf(xi2, bx2[tx]);
        float yy2 = fminf(yi2, bx3[tx]);
        float w2 = fmaxf(0.f, xx2 - xx1 + 1.f);
        float h2 = fmaxf(0.f, yy2 - yy1 + 1.f);
        float inter = w2 * h2;
        float ovr = inter / (ai + bar[tx] - inter);
        if (ovr > 0.3f) bkeep[tx] = 0;
      }
    }
    __syncthreads();
  }

  __shared__ int sel[32];
  if (tx == 0) {
    int s = 0;
    for (int r = 0; r < 256 && s < 32; ++r) if (bkeep[r]) sel[s++] = r;
    for (int r = 0; r < 256 && s < 32; ++r) if (!bkeep[r]) sel[s++] = r;
  }
  __syncthreads();
  if (tx < 32) {
    int r = sel[tx];
    int m = bkeep[r];
    int ob = (img * 3 + lvl) * 32 + tx;
    float d0 = 0.f, d1 = 0.f, d2 = 0.f, d3 = 0.f, d4 = 0.f;
    int c0 = 0, c1 = 0, c2 = 2, c3 = 2;
    if (m) {
      d0 = bx0[r]; d1 = bx1[r]; d2 = bx2[r]; d3 = bx3[r]; d4 = bsc[r];
      c0 = ((int)d0) / stride; c1 = ((int)d1) / stride;
      c2 = ((int)d2) / stride; c3 = ((int)d3) / stride;
    }
    dout[ob * 5 + 0] = d0; dout[ob * 5 + 1] = d1; dout[ob * 5 + 2] = d2;
    dout[ob * 5 + 3] = d3; dout[ob * 5 + 4] = d4;
    dout[960 + ob] = m ? 1.f : 0.f;
    coords[ob * 5 + 0] = c0; coords[ob * 5 + 1] = c1;
    coords[ob * 5 + 2] = c2; coords[ob * 5 + 3] = c3;
    coords[ob * 5 + 4] = m;
  }
}

// ---------------- ROI adaptive 7x7 maxpool (reads HWC f32) ----------------
__global__ __launch_bounds__(256) void roipool_kernel(
    const float* __restrict__ fh0, const float* __restrict__ fh1, const float* __restrict__ fh2,
    const int* __restrict__ coords, float* __restrict__ dout)
{
  int slot = blockIdx.x, lvl = blockIdx.y, img = blockIdx.z;
  int ob = (img * 3 + lvl) * 32 + slot;
  int c = threadIdx.x;
  const int* cw = coords + ob * 5;
  float* outp = dout + 1152 + (size_t)ob * 256 * 49 + (size_t)c * 49;
  int m = cw[4];
  if (!m) {
    #pragma unroll
    for (int i = 0; i < 49; ++i) outp[i] = 0.f;
    return;
  }
  int H = (lvl == 0) ? 64 : ((lvl == 1) ? 32 : 16);
  const float* f = ((lvl == 0) ? fh0 : ((lvl == 1) ? fh1 : fh2)) + (size_t)img * H * H * 256;
  int lox = cw[0], loy = cw[1], hix = cw[2], hiy = cw[3];
  int Lx = hix - lox, Ly = hiy - loy;
  for (int yi = 0; yi < 7; ++yi) {
    int ys = loy + (yi * Ly) / 7;
    int ye = loy + ((yi + 1) * Ly + 6) / 7;
    for (int xi = 0; xi < 7; ++xi) {
      int xs = lox + (xi * Lx) / 7;
      int xe = lox + ((xi + 1) * Lx + 6) / 7;
      float mx = -3.402823466e+38f;
      for (int y = ys; y < ye; ++y)
        for (int x = xs; x < xe; ++x)
          mx = fmaxf(mx, f[((size_t)y * H + x) * 256 + c]);
      outp[yi * 7 + xi] = mx;
    }
  }
}

// ---------------- host ----------------
extern "C" void kernel_launch(void* const* d_in, const int* in_sizes, int n_in,
                              void* d_out, int out_size, void* d_ws, size_t ws_size,
                              hipStream_t stream)
{
  (void)in_sizes; (void)n_in; (void)out_size; (void)ws_size;
  char* ws = (char*)d_ws;
  const float* layer2 = (const float*)d_in[0];
  const float* layer3 = (const float*)d_in[1];
  const float* layer4 = (const float*)d_in[2];
  const float* anch2  = (const float*)d_in[3];
  const float* anch3  = (const float*)d_in[4];
  const float* anch4  = (const float*)d_in[5];
  const float* hw1 = (const float*)d_in[6];
  const float* hg1 = (const float*)d_in[7];
  const float* hb1 = (const float*)d_in[8];
  const float* hm1 = (const float*)d_in[9];
  const float* hv1 = (const float*)d_in[10];
  const float* hw2 = (const float*)d_in[11];
  const float* hg2 = (const float*)d_in[12];
  const float* hb2 = (const float*)d_in[13];
  const float* hm2 = (const float*)d_in[14];
  const float* hv2 = (const float*)d_in[15];
  const float* clsw = (const float*)d_in[16];
  const float* locw = (const float*)d_in[17];
  float* dout = (float*)d_out;

  float* i0 = (float*)(ws + OFF_I0);
  float* i1 = (float*)(ws + OFF_I1);
  float* i2 = (float*)(ws + OFF_I2);
  float* l3f = (float*)(ws + OFF_L3F);
  float* h0 = (float*)(ws + OFF_H0);
  float* h1 = (float*)(ws + OFF_H1);
  float* h2 = (float*)(ws + OFF_H2);
  // fh aliases I (dead after conv1)
  float* fh0 = i0; float* fh1 = i1; float* fh2 = i2;
  float* logits = (float*)(ws + OFF_LOGITS);
  float* tvals  = (float*)(ws + OFF_TVALS);
  unsigned int* skey = (unsigned int*)(ws + OFF_SKEY);
  int* coords = (int*)(ws + OFF_COORDS);

  prep_bn_kernel<<<1, 256, 0, stream>>>(hg1, hb1, hm1, hv1, hg2, hb2, hm2, hv2, ws);
  prep_w_kernel<<<2048, 256, 0, stream>>>(hw1, hw2, clsw, locw, ws);

  // FPN merges into f32 HWC (and l3 f32 CHW for the l2 merge)
  fuse_kernel<<<dim3(4, 2), 256, 0, stream>>>(layer4, nullptr, nullptr, i2, 16, 4);
  fuse_kernel<<<dim3(16, 2), 256, 0, stream>>>(layer3, layer4, l3f, i1, 32, 5);
  fuse_kernel<<<dim3(64, 2), 256, 0, stream>>>(layer2, l3f, nullptr, i0, 64, 6);

  CArgs c1;
  c1.in0 = i0; c1.in1 = i1; c1.in2 = i2;
  c1.wh = (const short*)(ws + OFF_W1H); c1.wm = (const short*)(ws + OFF_W1M); c1.wl = (const short*)(ws + OFF_W1L);
  c1.out0 = h0; c1.out1 = h1; c1.out2 = h2;
  c1.inv = (const float*)(ws + OFF_INV1); c1.beta = (const float*)(ws + OFF_BETA1);
  c1.logits = nullptr; c1.tvals = nullptr;
  c1.ocw = 256; c1.mode = 0;
  conv_mfma_kernel<<<dim3(84, 4, 2), 256, 0, stream>>>(c1);

  CArgs c2;
  c2.in0 = h0; c2.in1 = h1; c2.in2 = h2;
  c2.wh = (const short*)(ws + OFF_W2H); c2.wm = (const short*)(ws + OFF_W2M); c2.wl = (const short*)(ws + OFF_W2L);
  c2.out0 = fh0; c2.out1 = fh1; c2.out2 = fh2;
  c2.inv = (const float*)(ws + OFF_INV2); c2.beta = (const float*)(ws + OFF_BETA2);
  c2.logits = nullptr; c2.tvals = nullptr;
  c2.ocw = 256; c2.mode = 1;
  conv_mfma_kernel<<<dim3(84, 4, 2), 256, 0, stream>>>(c2);

  CArgs cr;
  cr.in0 = fh0; cr.in1 = fh1; cr.in2 = fh2;
  cr.wh = (const short*)(ws + OFF_WRH); cr.wm = (const short*)(ws + OFF_WRM); cr.wl = (const short*)(ws + OFF_WRL);
  cr.out0 = nullptr; cr.out1 = nullptr; cr.out2 = nullptr;
  cr.inv = nullptr; cr.beta = nullptr;
  cr.logits = logits; cr.tvals = tvals;
  cr.ocw = 64; cr.mode = 2;
  conv_mfma_kernel<<<dim3(84, 1, 2), 256, 0, stream>>>(cr);

  postproc_kernel<<<dim3(3, 2), 256, 0, stream>>>(logits, tvals, anch2, anch3, anch4, skey, dout, coords);
  roipool_kernel<<<dim3(32, 3, 2), 256, 0, stream>>>(fh0, fh1, fh2, coords, dout);
}

// Round 3
// 591.910 us; speedup vs baseline: 1.9521x; 1.1110x over previous
//
#include <hip/hip_runtime.h>
#include <math.h>

typedef __attribute__((ext_vector_type(8))) short short8;
typedef __attribute__((ext_vector_type(16))) float f32x16;
typedef __attribute__((ext_vector_type(4))) float float4v;

// ---------------- bf16 helpers ----------------
__device__ __forceinline__ unsigned short f2bf(float f) {
  unsigned u = __float_as_uint(f);
  unsigned r = ((u >> 16) & 1u) + 0x7FFFu;
  return (unsigned short)((u + r) >> 16);
}
__device__ __forceinline__ float bf2f(unsigned short h) {
  return __uint_as_float(((unsigned)h) << 16);
}
__device__ __forceinline__ void split3(float v, short& h, short& m, short& l) {
  unsigned short hh = f2bf(v);
  float r1 = v - bf2f(hh);
  unsigned short mm = f2bf(r1);
  float r2 = r1 - bf2f(mm);
  unsigned short ll = f2bf(r2);
  h = (short)hh; m = (short)mm; l = (short)ll;
}
__device__ __forceinline__ short8 zero8() {
  short8 z;
  #pragma unroll
  for (int j = 0; j < 8; ++j) z[j] = 0;
  return z;
}

// ---------------- workspace layout (byte offsets) ----------------
#define OFF_W1H  0UL
#define OFF_W1M  1179648UL
#define OFF_W1L  2359296UL
#define OFF_W2H  3538944UL
#define OFF_W2M  4718592UL
#define OFF_W2L  5898240UL
#define OFF_WRH  7077888UL
#define OFF_WRM  7372800UL
#define OFF_WRL  7667712UL
#define OFF_I0   7962624UL    // 2*4096*256 f32 = 8388608 B  (aliased as fh0 after conv1)
#define OFF_I1   16351232UL   // 2*1024*256 f32 = 2097152 B  (fh1)
#define OFF_I2   18448384UL   // 2*256*256 f32 = 524288 B    (fh2)
#define OFF_L3F  18972672UL   // 2097152 B
#define OFF_H0   21069824UL   // 8388608
#define OFF_H1   29458432UL   // 2097152
#define OFF_H2   31555584UL   // 524288
#define OFF_INV1 32079872UL
#define OFF_BETA1 32080896UL
#define OFF_INV2 32081920UL
#define OFF_BETA2 32082944UL
#define OFF_LOGITS 32083968UL // 2*16128*4 = 129024
#define OFF_TVALS  32212992UL // 516096
#define OFF_SKEY   32729088UL // 129024
#define OFF_COORDS 32858112UL // 3840
// total ~32.9 MB

// out layout: dets[2][3][32][5] @0 (960) | mask[2][3][32] @960 (192) | rois @1152

// ---------------- prep: BN fold ----------------
__global__ __launch_bounds__(256) void prep_bn_kernel(
    const float* __restrict__ hg1, const float* __restrict__ hb1,
    const float* __restrict__ hm1, const float* __restrict__ hv1,
    const float* __restrict__ hg2, const float* __restrict__ hb2,
    const float* __restrict__ hm2, const float* __restrict__ hv2,
    char* __restrict__ ws)
{
  int t = threadIdx.x;
  float* inv1 = (float*)(ws + OFF_INV1);
  float* beta1 = (float*)(ws + OFF_BETA1);
  float* inv2 = (float*)(ws + OFF_INV2);
  float* beta2 = (float*)(ws + OFF_BETA2);
  float i1 = (float)((double)hg1[t] / sqrt((double)hv1[t] + 1e-5));
  inv1[t] = i1;
  beta1[t] = hb1[t] - hm1[t] * i1;
  float i2 = (float)((double)hg2[t] / sqrt((double)hv2[t] + 1e-5));
  inv2[t] = i2;
  beta2[t] = hb2[t] - hm2[t] * i2;
}

// ---------------- prep: weight split into [dydx][oc][ic] bf16 h/m/l ----------------
#define L1SZ 589824   // 9*256*256
#define RPNSZ 147456  // 9*64*256
__global__ __launch_bounds__(256) void prep_w_kernel(
    const float* __restrict__ hw1, const float* __restrict__ hw2,
    const float* __restrict__ clsw, const float* __restrict__ locw,
    char* __restrict__ ws)
{
  short* w1h = (short*)(ws + OFF_W1H);
  short* w1m = (short*)(ws + OFF_W1M);
  short* w1l = (short*)(ws + OFF_W1L);
  short* w2h = (short*)(ws + OFF_W2H);
  short* w2m = (short*)(ws + OFF_W2M);
  short* w2l = (short*)(ws + OFF_W2L);
  short* wrh = (short*)(ws + OFF_WRH);
  short* wrm = (short*)(ws + OFF_WRM);
  short* wrl = (short*)(ws + OFF_WRL);
  const int TOT = 2 * L1SZ + RPNSZ;
  for (int e = blockIdx.x * 256 + threadIdx.x; e < TOT; e += gridDim.x * 256) {
    float val; short *dh, *dm, *dl; int di;
    if (e < L1SZ) {
      int dydx = e >> 16, oc = (e >> 8) & 255, ic = e & 255;
      val = hw1[(size_t)(oc * 256 + ic) * 9 + dydx];
      dh = w1h; dm = w1m; dl = w1l; di = e;
    } else if (e < 2 * L1SZ) {
      int e2 = e - L1SZ;
      int dydx = e2 >> 16, oc = (e2 >> 8) & 255, ic = e2 & 255;
      val = hw2[(size_t)(oc * 256 + ic) * 9 + dydx];
      dh = w2h; dm = w2m; dl = w2l; di = e2;
    } else {
      int e3 = e - 2 * L1SZ;
      int dydx = e3 >> 14, oc = (e3 >> 8) & 63, ic = e3 & 255;
      if (oc < 3) val = clsw[(size_t)(oc * 256 + ic) * 9 + dydx];
      else if (oc < 15) val = locw[(size_t)((oc - 3) * 256 + ic) * 9 + dydx];
      else val = 0.f;
      dh = wrh; dm = wrm; dl = wrl; di = e3;
    }
    short h, m, l;
    split3(val, h, m, l);
    dh[di] = h; dm[di] = m; dl[di] = l;
  }
}

// ---------------- fuse: out_hwc = a_chw + upsample2x(b_chw); optional f32 CHW copy ----------------
__global__ __launch_bounds__(256) void fuse_kernel(
    const float* __restrict__ a, const float* __restrict__ bUp,
    float* __restrict__ f32chw, float* __restrict__ ohwc,
    int H, int logW)
{
  __shared__ float T[32][65];
  int HW = H * H;
  int img = blockIdx.y;
  const float* ap = a + (size_t)img * 256 * HW;
  const float* bp = bUp ? (bUp + (size_t)img * 256 * (HW >> 2)) : nullptr;
  float* fp = f32chw ? (f32chw + (size_t)img * 256 * HW) : nullptr;
  float* op = ohwc + (size_t)img * HW * 256;
  int p0 = blockIdx.x * 64;
  int tid = threadIdx.x;
  int px = tid & 63, cg = tid >> 6;
  int gp = p0 + px;
  int y = gp >> logW, x = gp & (H - 1);
  int px2 = tid >> 2, q = tid & 3;
  for (int c0 = 0; c0 < 256; c0 += 32) {
    #pragma unroll
    for (int cc = 0; cc < 8; ++cc) {
      int c = c0 + cg * 8 + cc;
      float v = ap[(size_t)c * HW + gp];
      if (bp) v += bp[(size_t)c * (HW >> 2) + (y >> 1) * (H >> 1) + (x >> 1)];
      if (fp) fp[(size_t)c * HW + gp] = v;
      T[cg * 8 + cc][px] = v;
    }
    __syncthreads();
    {
      size_t oa = (size_t)(p0 + px2) * 256 + c0 + q * 8;
      float4v v0, v1;
      #pragma unroll
      for (int j = 0; j < 4; ++j) v0[j] = T[q * 8 + j][px2];
      #pragma unroll
      for (int j = 0; j < 4; ++j) v1[j] = T[q * 8 + 4 + j][px2];
      *(float4v*)&op[oa] = v0;
      *(float4v*)&op[oa + 4] = v1;
    }
    __syncthreads();
  }
}

// ---------------- MFMA implicit-GEMM 3x3 conv ----------------
struct CArgs {
  const float* in0; const float* in1; const float* in2;   // f32 HWC per level
  const short* wh; const short* wm; const short* wl;      // [9][ocw][256]
  float* out0; float* out1; float* out2;                  // f32 HWC outs (modes 0,1)
  const float* inv; const float* beta;                    // BN folded
  float* logits; float* tvals;                            // mode 2
  int ocw; int mode;
};

__global__ __launch_bounds__(256) void conv_mfma_kernel(CArgs a)
{
  __shared__ short Ph[100 * 40], Pm[100 * 40], Pl[100 * 40];      // 24000 B
  __shared__ short WhS[2 * 64 * 40], WmS[2 * 64 * 40], WlS[2 * 64 * 40]; // 30720 B

  int bt = blockIdx.x;
  int lvl, tile;
  if (bt < 64) { lvl = 0; tile = bt; }
  else if (bt < 80) { lvl = 1; tile = bt - 64; }
  else { lvl = 2; tile = bt - 80; }
  int H = (lvl == 0) ? 64 : ((lvl == 1) ? 32 : 16);
  int HW = H * H;
  int tpr = H >> 3;
  int ty0 = (tile / tpr) * 8, tx0 = (tile % tpr) * 8;
  int img = blockIdx.z;
  int ocbase = blockIdx.y * 64;
  const float* inp = ((lvl == 0) ? a.in0 : ((lvl == 1) ? a.in1 : a.in2)) + (size_t)img * HW * 256;

  int tid = threadIdx.x;
  int l = tid & 63, w = tid >> 6;
  int wr = w >> 1, wc = w & 1;
  int row = l & 31, khalf = l >> 5;
  int m0 = wr * 32 + row;
  int my = m0 >> 3, mx = m0 & 7;
  int aBase = (my * 10 + mx) * 40 + khalf * 8;   // short offset, + dydx*... added later
  int bBase = (wc * 32 + row) * 40 + khalf * 8;

  f32x16 acc;
  #pragma unroll
  for (int j = 0; j < 16; ++j) acc[j] = 0.f;

  for (int icb = 0; icb < 8; ++icb) {
    // ---- stage input patch 10x10 x 32ic, split to 3x bf16 ----
    for (int u = tid; u < 400; u += 256) {
      int pxl = u >> 2, icq = u & 3;
      int py = pxl / 10, pxx = pxl - py * 10;
      int gy = ty0 + py - 1, gx = tx0 + pxx - 1;
      int lo = pxl * 40 + icq * 8;
      short8 sh, sm, sl;
      if ((unsigned)gy < (unsigned)H && (unsigned)gx < (unsigned)H) {
        const float* gptr = inp + (size_t)(gy * H + gx) * 256 + icb * 32 + icq * 8;
        #pragma unroll
        for (int j = 0; j < 8; ++j) {
          short hh, mm, ll;
          split3(gptr[j], hh, mm, ll);
          sh[j] = hh; sm[j] = mm; sl[j] = ll;
        }
      } else { sh = zero8(); sm = zero8(); sl = zero8(); }
      *(short8*)&Ph[lo] = sh;
      *(short8*)&Pm[lo] = sm;
      *(short8*)&Pl[lo] = sl;
    }
    __syncthreads();

    for (int g = 0; g < 5; ++g) {
      int dcount = (g == 4) ? 1 : 2;
      // ---- stage weights: dcount dydx slices of [64 oc][32 ic] x3 ----
      {
        int ocr = tid >> 2, icq = tid & 3;
        for (int d = 0; d < dcount; ++d) {
          int dydx = g * 2 + d;
          size_t ga = ((size_t)dydx * a.ocw + ocbase + ocr) * 256 + icb * 32 + icq * 8;
          int lo = (d * 64 + ocr) * 40 + icq * 8;
          *(short8*)&WhS[lo] = *(const short8*)&a.wh[ga];
          *(short8*)&WmS[lo] = *(const short8*)&a.wm[ga];
          *(short8*)&WlS[lo] = *(const short8*)&a.wl[ga];
        }
      }
      __syncthreads();
      // ---- MFMA ----
      for (int d = 0; d < dcount; ++d) {
        int dydx = g * 2 + d;
        int dy = dydx / 3, dx = dydx - dy * 3;
        int pA = aBase + (dy * 10 + dx) * 40;
        int pB = bBase + d * 64 * 40;
        #pragma unroll
        for (int k2 = 0; k2 < 2; ++k2) {
          int oA = pA + k2 * 16, oB = pB + k2 * 16;
          short8 ah = *(const short8*)&Ph[oA];
          short8 am = *(const short8*)&Pm[oA];
          short8 al = *(const short8*)&Pl[oA];
          short8 bh = *(const short8*)&WhS[oB];
          short8 bm = *(const short8*)&WmS[oB];
          short8 bl = *(const short8*)&WlS[oB];
          acc = __builtin_amdgcn_mfma_f32_32x32x16_bf16(ah, bh, acc, 0, 0, 0);
          acc = __builtin_amdgcn_mfma_f32_32x32x16_bf16(ah, bm, acc, 0, 0, 0);
          acc = __builtin_amdgcn_mfma_f32_32x32x16_bf16(am, bh, acc, 0, 0, 0);
          acc = __builtin_amdgcn_mfma_f32_32x32x16_bf16(ah, bl, acc, 0, 0, 0);
          acc = __builtin_amdgcn_mfma_f32_32x32x16_bf16(am, bm, acc, 0, 0, 0);
          acc = __builtin_amdgcn_mfma_f32_32x32x16_bf16(al, bh, acc, 0, 0, 0);
        }
      }
      __syncthreads();
    }
  }

  // ---- epilogue ----
  int oc = ocbase + wc * 32 + row;
  if (a.mode != 2) {
    float iv = a.inv[oc], bb = a.beta[oc];
    float* outp = ((lvl == 0) ? a.out0 : ((lvl == 1) ? a.out1 : a.out2)) + (size_t)img * HW * 256;
    #pragma unroll
    for (int r = 0; r < 16; ++r) {
      int ml = (r & 3) + 8 * (r >> 2) + 4 * khalf;
      int m = wr * 32 + ml;
      int y = ty0 + (m >> 3), x = tx0 + (m & 7);
      float v = acc[r] * iv + bb;
      v = (v >= 0.f) ? v : 0.01f * v;
      outp[(size_t)(y * H + x) * 256 + oc] = v;
    }
  } else {
    if (oc < 15) {
      int abase = (lvl == 0) ? 0 : ((lvl == 1) ? 12288 : 15360);
      #pragma unroll
      for (int r = 0; r < 16; ++r) {
        int ml = (r & 3) + 8 * (r >> 2) + 4 * khalf;
        int m = wr * 32 + ml;
        int y = ty0 + (m >> 3), x = tx0 + (m & 7);
        int gi = img * 16128 + abase + (y * H + x) * 3;
        float v = acc[r];
        if (oc < 3) a.logits[gi + oc] = v;
        else { int r2 = oc - 3; a.tvals[(size_t)(gi + (r2 >> 2)) * 4 + (r2 & 3)] = v; }
      }
    }
  }
}

// ---------------- decode helper ----------------
__device__ __forceinline__ void decode_one(const float* __restrict__ anch,
                                           const float* __restrict__ tv, int i,
                                           float& x1, float& y1, float& x2, float& y2)
{
  float t0 = tv[i * 4 + 0], t1 = tv[i * 4 + 1], t2 = tv[i * 4 + 2], t3 = tv[i * 4 + 3];
  float a0 = anch[i * 4 + 0], a1 = anch[i * 4 + 1], a2 = anch[i * 4 + 2], a3 = anch[i * 4 + 3];
  float aw = a2 - a0, ah = a3 - a1;
  float xx = a0 + t0 * aw;
  float yy = a1 + t1 * ah;
  float bw = aw * expf(t2);
  float bh = ah * expf(t3);
  x1 = fminf(fmaxf(xx, 0.f), 512.f);
  y1 = fminf(fmaxf(yy, 0.f), 512.f);
  x2 = fminf(fmaxf(xx + bw, 0.f), 512.f);
  y2 = fminf(fmaxf(yy + bh, 0.f), 512.f);
}

// ---------------- score kernel: keys for all anchors (wide grid) ----------------
__global__ __launch_bounds__(256) void score_kernel(
    const float* __restrict__ logits, const float* __restrict__ tvals,
    const float* __restrict__ anch0, const float* __restrict__ anch1, const float* __restrict__ anch2,
    unsigned int* __restrict__ skey)
{
  int g = blockIdx.x * 256 + threadIdx.x;
  if (g >= 2 * 16128) return;
  int img = g / 16128, r = g - img * 16128;
  int lvl = (r < 12288) ? 0 : ((r < 15360) ? 1 : 2);
  int abase = (lvl == 0) ? 0 : ((lvl == 1) ? 12288 : 15360);
  int stride = (lvl == 0) ? 8 : ((lvl == 1) ? 16 : 32);
  const float* anch = (lvl == 0) ? anch0 : ((lvl == 1) ? anch1 : anch2);
  int i = r - abase;
  float lv = logits[g];
  float sc = 1.f / (1.f + expf(-lv));
  float x1, y1, x2, y2;
  decode_one(anch, tvals + (size_t)(img * 16128 + abase) * 4, i, x1, y1, x2, y2);
  float minsz = 2.0f * (float)stride;
  bool valid = (sc > 0.5f) && ((x2 - x1) >= minsz) && ((y2 - y1) >= minsz);
  skey[g] = valid ? __float_as_uint(sc) : 0u;
}

// ---------------- postproc: radix-select -> rank-sort -> bitmask NMS -> outputs ----------------
__global__ __launch_bounds__(256) void postproc_kernel(
    const float* __restrict__ tvals,
    const float* __restrict__ anch0, const float* __restrict__ anch1, const float* __restrict__ anch2,
    const unsigned int* __restrict__ skey, float* __restrict__ dout, int* __restrict__ coords)
{
  int lvl = blockIdx.x, img = blockIdx.y;
  int N = (lvl == 0) ? 12288 : ((lvl == 1) ? 3072 : 768);
  int stride = (lvl == 0) ? 8 : ((lvl == 1) ? 16 : 32);
  int abase = (lvl == 0) ? 0 : ((lvl == 1) ? 12288 : 15360);
  const float* anch = (lvl == 0) ? anch0 : ((lvl == 1) ? anch1 : anch2);
  const float* tv = tvals + (size_t)(img * 16128 + abase) * 4;
  const unsigned int* sk = skey + img * 16128 + abase;
  int tx = threadIdx.x;

  __shared__ unsigned int hist[256];
  __shared__ int sh_digit, sh_nextS, sh_V;
  __shared__ unsigned long long slist[1024];
  __shared__ int scnt;
  __shared__ unsigned long long skey64[256];
  __shared__ float bx0[256], bx1[256], bx2[256], bx3[256], bar[256], bsc[256];
  __shared__ unsigned long long rsup[256][4];
  __shared__ unsigned long long kinit[4], kfin[4];
  __shared__ unsigned char bkeepArr[256];
  __shared__ int sel[32];

  // ---- radix select: 3 passes of 8 bits on low-24 key bits ----
  unsigned int prefix = 0;
  int needed = 256;
  for (int pass = 0; pass < 3; ++pass) {
    int shift = 16 - 8 * pass;
    hist[tx] = 0u;
    __syncthreads();
    for (int i = tx; i < N; i += 256) {
      unsigned int v = sk[i];
      if (v != 0u) {
        unsigned int k24 = v & 0xFFFFFFu;
        if (pass == 0 || (k24 >> (shift + 8)) == prefix)
          atomicAdd(&hist[(k24 >> shift) & 255u], 1u);
      }
    }
    __syncthreads();
    unsigned int S = 0;
    for (int b = 0; b < 256; ++b) {
      unsigned int h = hist[b];
      S += (b >= tx) ? h : 0u;
    }
    if (pass == 0 && tx == 0) sh_V = (int)S;   // S at tx==0 is the total
    __syncthreads();
    if (pass == 0) needed = (sh_V < 256) ? sh_V : 256;
    if (sh_V > 0) {
      int Snext = (int)S - (int)hist[tx];
      if ((int)S >= needed && Snext < needed) { sh_digit = tx; sh_nextS = Snext; }
    }
    __syncthreads();
    if (sh_V > 0) {
      prefix = (prefix << 8) | (unsigned int)sh_digit;
      needed = needed - sh_nextS;
    }
    __syncthreads();
  }

  // ---- collect candidates (key24 >= prefix), build u64 keys ----
  if (tx == 0) scnt = 0;
  #pragma unroll
  for (int q = 0; q < 4; ++q) slist[tx + q * 256] = 0ull;
  __syncthreads();
  if (sh_V > 0) {
    for (int i = tx; i < N; i += 256) {
      unsigned int v = sk[i];
      if (v != 0u && (v & 0xFFFFFFu) >= prefix) {
        int p = atomicAdd(&scnt, 1);
        if (p < 1024)
          slist[p] = ((unsigned long long)v << 32) | (unsigned long long)(0xFFFFFFFFu - (unsigned)i);
      }
    }
  }
  __syncthreads();
  int M = scnt < 1024 ? scnt : 1024;

  // ---- rank sort (keys unique): sorted[rank] = key, keep top 256 ----
  skey64[tx] = 0ull;
  __syncthreads();
  for (int it = tx; it < M; it += 256) {
    unsigned long long K = slist[it];
    int rank = 0;
    for (int j = 0; j < M; ++j) rank += (slist[j] > K) ? 1 : 0;
    if (rank < 256) skey64[rank] = K;
  }
  __syncthreads();

  // ---- decode 256 slots ----
  {
    unsigned long long key = skey64[tx];
    float x1 = 0.f, y1 = 0.f, x2 = 0.f, y2 = 0.f, sc = 0.f;
    if (key != 0ull) {
      sc = __uint_as_float((unsigned int)(key >> 32));
      int idx = (int)(0xFFFFFFFFu - (unsigned int)(key & 0xFFFFFFFFull));
      decode_one(anch, tv, idx, x1, y1, x2, y2);
    }
    bx0[tx] = x1; bx1[tx] = y1; bx2[tx] = x2; bx3[tx] = y2;
    bsc[tx] = sc;
    bar[tx] = (x2 - x1 + 1.f) * (y2 - y1 + 1.f);
    unsigned long long b = __ballot(sc > 0.5f);
    if ((tx & 63) == 0) kinit[tx >> 6] = b;
  }
  __syncthreads();

  // ---- suppression rows: bits j>i with IoU>0.3 ----
  {
    float xi1 = bx0[tx], yi1 = bx1[tx], xi2 = bx2[tx], yi2 = bx3[tx], ai = bar[tx];
    #pragma unroll
    for (int w = 0; w < 4; ++w) {
      unsigned long long rr = 0ull;
      int j0 = w * 64;
      int js = (tx + 1 > j0) ? (tx + 1) : j0;
      for (int j = js; j < j0 + 64; ++j) {
        float xx1 = fmaxf(xi1, bx0[j]);
        float yy1 = fmaxf(yi1, bx1[j]);
        float xx2 = fminf(xi2, bx2[j]);
        float yy2 = fminf(yi2, bx3[j]);
        float ww = fmaxf(0.f, xx2 - xx1 + 1.f);
        float hh = fmaxf(0.f, yy2 - yy1 + 1.f);
        float inter = ww * hh;
        float ovr = inter / (ai + bar[j] - inter);
        rr |= (ovr > 0.3f) ? (1ull << (j & 63)) : 0ull;
      }
      rsup[tx][w] = rr;
    }
  }
  __syncthreads();

  // ---- greedy propagation (single thread, branchless bitmask) ----
  if (tx == 0) {
    unsigned long long k0 = kinit[0], k1 = kinit[1], k2 = kinit[2], k3 = kinit[3];
    #define NMS_CHUNK(W, KW) \
      for (int i = W * 64; i < W * 64 + 64; ++i) { \
        unsigned long long live = 0ull - ((KW >> (i & 63)) & 1ull); \
        k0 &= ~(rsup[i][0] & live); \
        k1 &= ~(rsup[i][1] & live); \
        k2 &= ~(rsup[i][2] & live); \
        k3 &= ~(rsup[i][3] & live); \
      }
    NMS_CHUNK(0, k0)
    NMS_CHUNK(1, k1)
    NMS_CHUNK(2, k2)
    NMS_CHUNK(3, k3)
    #undef NMS_CHUNK
    kfin[0] = k0; kfin[1] = k1; kfin[2] = k2; kfin[3] = k3;
  }
  __syncthreads();
  bkeepArr[tx] = (unsigned char)((kfin[tx >> 6] >> (tx & 63)) & 1ull);
  __syncthreads();

  // ---- stable order: kept first, take 32 ----
  if (tx == 0) {
    int s = 0;
    for (int r = 0; r < 256 && s < 32; ++r) if (bkeepArr[r]) sel[s++] = r;
    for (int r = 0; r < 256 && s < 32; ++r) if (!bkeepArr[r]) sel[s++] = r;
  }
  __syncthreads();
  if (tx < 32) {
    int r = sel[tx];
    int m = bkeepArr[r];
    int ob = (img * 3 + lvl) * 32 + tx;
    float d0 = 0.f, d1 = 0.f, d2 = 0.f, d3 = 0.f, d4 = 0.f;
    int c0 = 0, c1 = 0, c2 = 2, c3 = 2;
    if (m) {
      d0 = bx0[r]; d1 = bx1[r]; d2 = bx2[r]; d3 = bx3[r]; d4 = bsc[r];
      c0 = ((int)d0) / stride; c1 = ((int)d1) / stride;
      c2 = ((int)d2) / stride; c3 = ((int)d3) / stride;
    }
    dout[ob * 5 + 0] = d0; dout[ob * 5 + 1] = d1; dout[ob * 5 + 2] = d2;
    dout[ob * 5 + 3] = d3; dout[ob * 5 + 4] = d4;
    dout[960 + ob] = m ? 1.f : 0.f;
    coords[ob * 5 + 0] = c0; coords[ob * 5 + 1] = c1;
    coords[ob * 5 + 2] = c2; coords[ob * 5 + 3] = c3;
    coords[ob * 5 + 4] = m;
  }
}

// ---------------- ROI adaptive 7x7 maxpool (reads HWC f32) ----------------
__global__ __launch_bounds__(256) void roipool_kernel(
    const float* __restrict__ fh0, const float* __restrict__ fh1, const float* __restrict__ fh2,
    const int* __restrict__ coords, float* __restrict__ dout)
{
  int slot = blockIdx.x, lvl = blockIdx.y, img = blockIdx.z;
  int ob = (img * 3 + lvl) * 32 + slot;
  int c = threadIdx.x;
  const int* cw = coords + ob * 5;
  float* outp = dout + 1152 + (size_t)ob * 256 * 49 + (size_t)c * 49;
  int m = cw[4];
  if (!m) {
    #pragma unroll
    for (int i = 0; i < 49; ++i) outp[i] = 0.f;
    return;
  }
  int H = (lvl == 0) ? 64 : ((lvl == 1) ? 32 : 16);
  const float* f = ((lvl == 0) ? fh0 : ((lvl == 1) ? fh1 : fh2)) + (size_t)img * H * H * 256;
  int lox = cw[0], loy = cw[1], hix = cw[2], hiy = cw[3];
  int Lx = hix - lox, Ly = hiy - loy;
  for (int yi = 0; yi < 7; ++yi) {
    int ys = loy + (yi * Ly) / 7;
    int ye = loy + ((yi + 1) * Ly + 6) / 7;
    for (int xi = 0; xi < 7; ++xi) {
      int xs = lox + (xi * Lx) / 7;
      int xe = lox + ((xi + 1) * Lx + 6) / 7;
      float mx = -3.402823466e+38f;
      for (int y = ys; y < ye; ++y)
        for (int x = xs; x < xe; ++x)
          mx = fmaxf(mx, f[((size_t)y * H + x) * 256 + c]);
      outp[yi * 7 + xi] = mx;
    }
  }
}

// ---------------- host ----------------
extern "C" void kernel_launch(void* const* d_in, const int* in_sizes, int n_in,
                              void* d_out, int out_size, void* d_ws, size_t ws_size,
                              hipStream_t stream)
{
  (void)in_sizes; (void)n_in; (void)out_size; (void)ws_size;
  char* ws = (char*)d_ws;
  const float* layer2 = (const float*)d_in[0];
  const float* layer3 = (const float*)d_in[1];
  const float* layer4 = (const float*)d_in[2];
  const float* anch2  = (const float*)d_in[3];
  const float* anch3  = (const float*)d_in[4];
  const float* anch4  = (const float*)d_in[5];
  const float* hw1 = (const float*)d_in[6];
  const float* hg1 = (const float*)d_in[7];
  const float* hb1 = (const float*)d_in[8];
  const float* hm1 = (const float*)d_in[9];
  const float* hv1 = (const float*)d_in[10];
  const float* hw2 = (const float*)d_in[11];
  const float* hg2 = (const float*)d_in[12];
  const float* hb2 = (const float*)d_in[13];
  const float* hm2 = (const float*)d_in[14];
  const float* hv2 = (const float*)d_in[15];
  const float* clsw = (const float*)d_in[16];
  const float* locw = (const float*)d_in[17];
  float* dout = (float*)d_out;

  float* i0 = (float*)(ws + OFF_I0);
  float* i1 = (float*)(ws + OFF_I1);
  float* i2 = (float*)(ws + OFF_I2);
  float* l3f = (float*)(ws + OFF_L3F);
  float* h0 = (float*)(ws + OFF_H0);
  float* h1 = (float*)(ws + OFF_H1);
  float* h2 = (float*)(ws + OFF_H2);
  // fh aliases I (dead after conv1)
  float* fh0 = i0; float* fh1 = i1; float* fh2 = i2;
  float* logits = (float*)(ws + OFF_LOGITS);
  float* tvals  = (float*)(ws + OFF_TVALS);
  unsigned int* skey = (unsigned int*)(ws + OFF_SKEY);
  int* coords = (int*)(ws + OFF_COORDS);

  prep_bn_kernel<<<1, 256, 0, stream>>>(hg1, hb1, hm1, hv1, hg2, hb2, hm2, hv2, ws);
  prep_w_kernel<<<2048, 256, 0, stream>>>(hw1, hw2, clsw, locw, ws);

  // FPN merges into f32 HWC (and l3 f32 CHW for the l2 merge)
  fuse_kernel<<<dim3(4, 2), 256, 0, stream>>>(layer4, nullptr, nullptr, i2, 16, 4);
  fuse_kernel<<<dim3(16, 2), 256, 0, stream>>>(layer3, layer4, l3f, i1, 32, 5);
  fuse_kernel<<<dim3(64, 2), 256, 0, stream>>>(layer2, l3f, nullptr, i0, 64, 6);

  CArgs c1;
  c1.in0 = i0; c1.in1 = i1; c1.in2 = i2;
  c1.wh = (const short*)(ws + OFF_W1H); c1.wm = (const short*)(ws + OFF_W1M); c1.wl = (const short*)(ws + OFF_W1L);
  c1.out0 = h0; c1.out1 = h1; c1.out2 = h2;
  c1.inv = (const float*)(ws + OFF_INV1); c1.beta = (const float*)(ws + OFF_BETA1);
  c1.logits = nullptr; c1.tvals = nullptr;
  c1.ocw = 256; c1.mode = 0;
  conv_mfma_kernel<<<dim3(84, 4, 2), 256, 0, stream>>>(c1);

  CArgs c2;
  c2.in0 = h0; c2.in1 = h1; c2.in2 = h2;
  c2.wh = (const short*)(ws + OFF_W2H); c2.wm = (const short*)(ws + OFF_W2M); c2.wl = (const short*)(ws + OFF_W2L);
  c2.out0 = fh0; c2.out1 = fh1; c2.out2 = fh2;
  c2.inv = (const float*)(ws + OFF_INV2); c2.beta = (const float*)(ws + OFF_BETA2);
  c2.logits = nullptr; c2.tvals = nullptr;
  c2.ocw = 256; c2.mode = 1;
  conv_mfma_kernel<<<dim3(84, 4, 2), 256, 0, stream>>>(c2);

  CArgs cr;
  cr.in0 = fh0; cr.in1 = fh1; cr.in2 = fh2;
  cr.wh = (const short*)(ws + OFF_WRH); cr.wm = (const short*)(ws + OFF_WRM); cr.wl = (const short*)(ws + OFF_WRL);
  cr.out0 = nullptr; cr.out1 = nullptr; cr.out2 = nullptr;
  cr.inv = nullptr; cr.beta = nullptr;
  cr.logits = logits; cr.tvals = tvals;
  cr.ocw = 64; cr.mode = 2;
  conv_mfma_kernel<<<dim3(84, 1, 2), 256, 0, stream>>>(cr);

  score_kernel<<<126, 256, 0, stream>>>(logits, tvals, anch2, anch3, anch4, skey);
  postproc_kernel<<<dim3(3, 2), 256, 0, stream>>>(tvals, anch2, anch3, anch4, skey, dout, coords);
  roipool_kernel<<<dim3(32, 3, 2), 256, 0, stream>>>(fh0, fh1, fh2, coords, dout);
}

// Round 4
// 535.668 us; speedup vs baseline: 2.1571x; 1.1050x over previous
//
#include <hip/hip_runtime.h>
#include <math.h>

typedef __attribute__((ext_vector_type(8))) _Float16 f16x8;
typedef __attribute__((ext_vector_type(16))) float f32x16;
typedef __attribute__((ext_vector_type(4))) float float4v;

// ---------------- fp16 split2 helpers: v = h + l/4096 ----------------
__device__ __forceinline__ void split2(float v, _Float16& h, _Float16& l) {
  h = (_Float16)v;
  l = (_Float16)((v - (float)h) * 4096.0f);
}

// ---------------- workspace layout (byte offsets) ----------------
#define OFF_W1H  0UL          // 9*256*256*2 = 1179648
#define OFF_W1L  1179648UL
#define OFF_W2H  2359296UL
#define OFF_W2L  3538944UL
#define OFF_WRH  4718592UL    // 9*32*256*2 = 147456
#define OFF_WRL  4866048UL
#define OFF_I0H  5013504UL    // 2*4096*256*2 = 4194304  (aliased as conv2-out F after conv1)
#define OFF_I0L  9207808UL
#define OFF_I1H  13402112UL   // 2*1024*256*2 = 1048576
#define OFF_I1L  14450688UL
#define OFF_I2H  15499264UL   // 2*256*256*2 = 262144
#define OFF_I2L  15761408UL
#define OFF_L3F  16023552UL   // f32 CHW 2*256*1024*4 = 2097152
#define OFF_H0H  18120704UL
#define OFF_H0L  22315008UL
#define OFF_H1H  26509312UL
#define OFF_H1L  27557888UL
#define OFF_H2H  28606464UL
#define OFF_H2L  28868608UL
#define OFF_LOGITS 29130752UL // 2*16128*4 = 129024
#define OFF_TVALS  29259776UL // 516096
#define OFF_SKEY   29775872UL // 129024
#define OFF_COORDS 29904896UL // 3840
// total ~29.9 MB

// out layout: dets[2][3][32][5] @0 (960) | mask[2][3][32] @960 (192) | rois @1152

// ---------------- prep: BN fold ----------------
__global__ __launch_bounds__(256) void prep_bn_kernel(
    const float* __restrict__ hg1, const float* __restrict__ hb1,
    const float* __restrict__ hm1, const float* __restrict__ hv1,
    const float* __restrict__ hg2, const float* __restrict__ hb2,
    const float* __restrict__ hm2, const float* __restrict__ hv2,
    float* __restrict__ inv1, float* __restrict__ beta1,
    float* __restrict__ inv2, float* __restrict__ beta2)
{
  int t = threadIdx.x;
  float i1 = (float)((double)hg1[t] / sqrt((double)hv1[t] + 1e-5));
  inv1[t] = i1;
  beta1[t] = hb1[t] - hm1[t] * i1;
  float i2 = (float)((double)hg2[t] / sqrt((double)hv2[t] + 1e-5));
  inv2[t] = i2;
  beta2[t] = hb2[t] - hm2[t] * i2;
}

// ---------------- prep: weight split into [dydx][oc][ic] fp16 H/L ----------------
#define L1SZ 589824   // 9*256*256
#define RPNSZ 73728   // 9*32*256
__global__ __launch_bounds__(256) void prep_w_kernel(
    const float* __restrict__ hw1, const float* __restrict__ hw2,
    const float* __restrict__ clsw, const float* __restrict__ locw,
    char* __restrict__ ws)
{
  _Float16* w1h = (_Float16*)(ws + OFF_W1H);
  _Float16* w1l = (_Float16*)(ws + OFF_W1L);
  _Float16* w2h = (_Float16*)(ws + OFF_W2H);
  _Float16* w2l = (_Float16*)(ws + OFF_W2L);
  _Float16* wrh = (_Float16*)(ws + OFF_WRH);
  _Float16* wrl = (_Float16*)(ws + OFF_WRL);
  const int TOT = 2 * L1SZ + RPNSZ;
  for (int e = blockIdx.x * 256 + threadIdx.x; e < TOT; e += gridDim.x * 256) {
    float val; _Float16 *dh, *dl; int di;
    if (e < L1SZ) {
      int dydx = e >> 16, oc = (e >> 8) & 255, ic = e & 255;
      val = hw1[(size_t)(oc * 256 + ic) * 9 + dydx];
      dh = w1h; dl = w1l; di = e;
    } else if (e < 2 * L1SZ) {
      int e2 = e - L1SZ;
      int dydx = e2 >> 16, oc = (e2 >> 8) & 255, ic = e2 & 255;
      val = hw2[(size_t)(oc * 256 + ic) * 9 + dydx];
      dh = w2h; dl = w2l; di = e2;
    } else {
      int e3 = e - 2 * L1SZ;
      int dydx = e3 >> 13, oc = (e3 >> 8) & 31, ic = e3 & 255;
      if (oc < 3) val = clsw[(size_t)(oc * 256 + ic) * 9 + dydx];
      else if (oc < 15) val = locw[(size_t)((oc - 3) * 256 + ic) * 9 + dydx];
      else val = 0.f;
      dh = wrh; dl = wrl; di = e3;
    }
    _Float16 h, l;
    split2(val, h, l);
    dh[di] = h; dl[di] = l;
  }
}

// ---------------- fuse: hwc_f16(H,L) = a_chw + upsample2x(b_chw); optional f32 CHW copy ----------------
__global__ __launch_bounds__(256) void fuse_kernel(
    const float* __restrict__ a, const float* __restrict__ bUp,
    float* __restrict__ f32chw, _Float16* __restrict__ oH, _Float16* __restrict__ oL,
    int H, int logW)
{
  __shared__ float T[32][65];
  int HW = H * H;
  int img = blockIdx.y;
  const float* ap = a + (size_t)img * 256 * HW;
  const float* bp = bUp ? (bUp + (size_t)img * 256 * (HW >> 2)) : nullptr;
  float* fp = f32chw ? (f32chw + (size_t)img * 256 * HW) : nullptr;
  _Float16* oHp = oH + (size_t)img * HW * 256;
  _Float16* oLp = oL + (size_t)img * HW * 256;
  int p0 = blockIdx.x * 64;
  int tid = threadIdx.x;
  int px = tid & 63, cg = tid >> 6;
  int gp = p0 + px;
  int y = gp >> logW, x = gp & (H - 1);
  int px2 = tid >> 2, q = tid & 3;
  for (int c0 = 0; c0 < 256; c0 += 32) {
    #pragma unroll
    for (int cc = 0; cc < 8; ++cc) {
      int c = c0 + cg * 8 + cc;
      float v = ap[(size_t)c * HW + gp];
      if (bp) v += bp[(size_t)c * (HW >> 2) + (y >> 1) * (H >> 1) + (x >> 1)];
      if (fp) fp[(size_t)c * HW + gp] = v;
      T[cg * 8 + cc][px] = v;
    }
    __syncthreads();
    {
      size_t oa = (size_t)(p0 + px2) * 256 + c0 + q * 8;
      f16x8 hs, ls;
      #pragma unroll
      for (int j = 0; j < 8; ++j) {
        float v = T[q * 8 + j][px2];
        _Float16 h, l;
        split2(v, h, l);
        hs[j] = h; ls[j] = l;
      }
      *(f16x8*)&oHp[oa] = hs;
      *(f16x8*)&oLp[oa] = ls;
    }
    __syncthreads();
  }
}

// ---------------- MFMA implicit-GEMM 3x3 conv: 1 wave/block, 64px x (NSUB*32)oc ----------------
struct CArgs {
  const _Float16* inH[3]; const _Float16* inL[3];   // fp16 HWC per level
  const _Float16* wH; const _Float16* wL;           // [9][ocw][256]
  _Float16* outH[3]; _Float16* outL[3];             // fp16 HWC outs (mode 0)
  const float* inv; const float* beta;              // BN folded
  float* logits; float* tvals;                      // mode 2
  int ocw; int mode;                                // 0 head, 2 rpn
};

template<int NSUB>
__global__ __launch_bounds__(64) void conv_mfma_kernel(CArgs a)
{
  __shared__ _Float16 Ph[100 * 40], Pl[100 * 40];   // 16000 B

  int bt = blockIdx.x;
  int lvl, tile;
  if (bt < 64) { lvl = 0; tile = bt; }
  else if (bt < 80) { lvl = 1; tile = bt - 64; }
  else { lvl = 2; tile = bt - 80; }
  int H = (lvl == 0) ? 64 : ((lvl == 1) ? 32 : 16);
  int HW = H * H;
  int tpr = H >> 3;
  int ty0 = (tile / tpr) * 8, tx0 = (tile % tpr) * 8;
  int img = blockIdx.z;
  int ocb = blockIdx.y * 64;
  const _Float16* inH = a.inH[lvl] + (size_t)img * HW * 256;
  const _Float16* inL = a.inL[lvl] + (size_t)img * HW * 256;

  int lane = threadIdx.x;
  int row = lane & 31, khalf = lane >> 5;

  f32x16 acc1[2][NSUB];   // h*h
  f32x16 acc2[2][NSUB];   // h*l' + l'*h  (scaled by 4096)
  #pragma unroll
  for (int ms = 0; ms < 2; ++ms)
    #pragma unroll
    for (int os = 0; os < NSUB; ++os)
      #pragma unroll
      for (int j = 0; j < 16; ++j) { acc1[ms][os][j] = 0.f; acc2[ms][os][j] = 0.f; }

  // A-read base offsets (per m-subtile; dydx offset added in loop)
  int aoff[2];
  #pragma unroll
  for (int ms = 0; ms < 2; ++ms) {
    int m = ms * 32 + row;
    aoff[ms] = ((m >> 3) * 10 + (m & 7)) * 40 + khalf * 8;
  }

  for (int icb = 0; icb < 8; ++icb) {
    // ---- stage 10x10x32 patch (H,L) ----
    for (int u = lane; u < 400; u += 64) {
      int pxl = u >> 2, icq = u & 3;
      int py = pxl / 10, pxx = pxl - py * 10;
      int gy = ty0 + py - 1, gx = tx0 + pxx - 1;
      int lo = pxl * 40 + icq * 8;
      if ((unsigned)gy < (unsigned)H && (unsigned)gx < (unsigned)H) {
        size_t ga = (size_t)(gy * H + gx) * 256 + icb * 32 + icq * 8;
        *(f16x8*)&Ph[lo] = *(const f16x8*)&inH[ga];
        *(f16x8*)&Pl[lo] = *(const f16x8*)&inL[ga];
      } else {
        f16x8 z;
        #pragma unroll
        for (int j = 0; j < 8; ++j) z[j] = (_Float16)0.f;
        *(f16x8*)&Ph[lo] = z;
        *(f16x8*)&Pl[lo] = z;
      }
    }
    __syncthreads();

    for (int dydx = 0; dydx < 9; ++dydx) {
      int dy = dydx / 3, dx = dydx - dy * 3;
      int pshift = (dy * 10 + dx) * 40;
      #pragma unroll
      for (int k2 = 0; k2 < 2; ++k2) {
        // B frags from global (L2-resident), layout matches lanes exactly
        f16x8 bh[NSUB], bl[NSUB];
        #pragma unroll
        for (int os = 0; os < NSUB; ++os) {
          size_t ga = ((size_t)(dydx * a.ocw) + ocb + os * 32 + row) * 256
                      + icb * 32 + k2 * 16 + khalf * 8;
          bh[os] = *(const f16x8*)&a.wH[ga];
          bl[os] = *(const f16x8*)&a.wL[ga];
        }
        // A frags from LDS
        f16x8 ah[2], al[2];
        #pragma unroll
        for (int ms = 0; ms < 2; ++ms) {
          int off = aoff[ms] + pshift + k2 * 16;
          ah[ms] = *(const f16x8*)&Ph[off];
          al[ms] = *(const f16x8*)&Pl[off];
        }
        #pragma unroll
        for (int ms = 0; ms < 2; ++ms)
          #pragma unroll
          for (int os = 0; os < NSUB; ++os) {
            acc1[ms][os] = __builtin_amdgcn_mfma_f32_32x32x16_f16(ah[ms], bh[os], acc1[ms][os], 0, 0, 0);
            acc2[ms][os] = __builtin_amdgcn_mfma_f32_32x32x16_f16(ah[ms], bl[os], acc2[ms][os], 0, 0, 0);
            acc2[ms][os] = __builtin_amdgcn_mfma_f32_32x32x16_f16(al[ms], bh[os], acc2[ms][os], 0, 0, 0);
          }
      }
    }
    __syncthreads();
  }

  // ---- epilogue ----
  if (a.mode == 0) {
    _Float16* outH = a.outH[lvl] + (size_t)img * HW * 256;
    _Float16* outL = a.outL[lvl] + (size_t)img * HW * 256;
    #pragma unroll
    for (int ms = 0; ms < 2; ++ms)
      #pragma unroll
      for (int os = 0; os < NSUB; ++os) {
        int oc = ocb + os * 32 + row;
        float iv = a.inv[oc], bb = a.beta[oc];
        #pragma unroll
        for (int r = 0; r < 16; ++r) {
          int ml = (r & 3) + 8 * (r >> 2) + 4 * khalf;
          int m = ms * 32 + ml;
          int y = ty0 + (m >> 3), x = tx0 + (m & 7);
          float v = acc1[ms][os][r] + acc2[ms][os][r] * (1.f / 4096.f);
          v = v * iv + bb;
          v = (v >= 0.f) ? v : 0.01f * v;
          _Float16 h, l;
          split2(v, h, l);
          size_t oa = (size_t)(y * H + x) * 256 + oc;
          outH[oa] = h;
          outL[oa] = l;
        }
      }
  } else {
    int oc = ocb + row;   // NSUB==1
    if (oc < 15) {
      int abase = (lvl == 0) ? 0 : ((lvl == 1) ? 12288 : 15360);
      #pragma unroll
      for (int ms = 0; ms < 2; ++ms)
        #pragma unroll
        for (int r = 0; r < 16; ++r) {
          int ml = (r & 3) + 8 * (r >> 2) + 4 * khalf;
          int m = ms * 32 + ml;
          int y = ty0 + (m >> 3), x = tx0 + (m & 7);
          int gi = img * 16128 + abase + (y * H + x) * 3;
          float v = acc1[ms][0][r] + acc2[ms][0][r] * (1.f / 4096.f);
          if (oc < 3) a.logits[gi + oc] = v;
          else { int r2 = oc - 3; a.tvals[(size_t)(gi + (r2 >> 2)) * 4 + (r2 & 3)] = v; }
        }
    }
  }
}

// ---------------- decode helper ----------------
__device__ __forceinline__ void decode_one(const float* __restrict__ anch,
                                           const float* __restrict__ tv, int i,
                                           float& x1, float& y1, float& x2, float& y2)
{
  float t0 = tv[i * 4 + 0], t1 = tv[i * 4 + 1], t2 = tv[i * 4 + 2], t3 = tv[i * 4 + 3];
  float a0 = anch[i * 4 + 0], a1 = anch[i * 4 + 1], a2 = anch[i * 4 + 2], a3 = anch[i * 4 + 3];
  float aw = a2 - a0, ah = a3 - a1;
  float xx = a0 + t0 * aw;
  float yy = a1 + t1 * ah;
  float bw = aw * expf(t2);
  float bh = ah * expf(t3);
  x1 = fminf(fmaxf(xx, 0.f), 512.f);
  y1 = fminf(fmaxf(yy, 0.f), 512.f);
  x2 = fminf(fmaxf(xx + bw, 0.f), 512.f);
  y2 = fminf(fmaxf(yy + bh, 0.f), 512.f);
}

// ---------------- score kernel ----------------
__global__ __launch_bounds__(256) void score_kernel(
    const float* __restrict__ logits, const float* __restrict__ tvals,
    const float* __restrict__ anch0, const float* __restrict__ anch1, const float* __restrict__ anch2,
    unsigned int* __restrict__ skey)
{
  int g = blockIdx.x * 256 + threadIdx.x;
  if (g >= 2 * 16128) return;
  int img = g / 16128, r = g - img * 16128;
  int lvl = (r < 12288) ? 0 : ((r < 15360) ? 1 : 2);
  int abase = (lvl == 0) ? 0 : ((lvl == 1) ? 12288 : 15360);
  int stride = (lvl == 0) ? 8 : ((lvl == 1) ? 16 : 32);
  const float* anch = (lvl == 0) ? anch0 : ((lvl == 1) ? anch1 : anch2);
  int i = r - abase;
  float lv = logits[g];
  float sc = 1.f / (1.f + expf(-lv));
  float x1, y1, x2, y2;
  decode_one(anch, tvals + (size_t)(img * 16128 + abase) * 4, i, x1, y1, x2, y2);
  float minsz = 2.0f * (float)stride;
  bool valid = (sc > 0.5f) && ((x2 - x1) >= minsz) && ((y2 - y1) >= minsz);
  skey[g] = valid ? __float_as_uint(sc) : 0u;
}

// ---------------- postproc: radix-select -> rank-sort -> bitmask NMS -> outputs ----------------
__global__ __launch_bounds__(256) void postproc_kernel(
    const float* __restrict__ tvals,
    const float* __restrict__ anch0, const float* __restrict__ anch1, const float* __restrict__ anch2,
    const unsigned int* __restrict__ skey, float* __restrict__ dout, int* __restrict__ coords)
{
  int lvl = blockIdx.x, img = blockIdx.y;
  int N = (lvl == 0) ? 12288 : ((lvl == 1) ? 3072 : 768);
  int stride = (lvl == 0) ? 8 : ((lvl == 1) ? 16 : 32);
  int abase = (lvl == 0) ? 0 : ((lvl == 1) ? 12288 : 15360);
  const float* anch = (lvl == 0) ? anch0 : ((lvl == 1) ? anch1 : anch2);
  const float* tv = tvals + (size_t)(img * 16128 + abase) * 4;
  const unsigned int* sk = skey + img * 16128 + abase;
  int tx = threadIdx.x;

  __shared__ unsigned int hist[256];
  __shared__ int sh_digit, sh_nextS, sh_V;
  __shared__ unsigned long long slist[1024];
  __shared__ int scnt;
  __shared__ unsigned long long skey64[256];
  __shared__ float bx0[256], bx1[256], bx2[256], bx3[256], bar[256], bsc[256];
  __shared__ unsigned long long rsup[256][4];
  __shared__ unsigned long long kinit[4], kfin[4];
  __shared__ unsigned char bkeepArr[256];
  __shared__ int sel[32];

  // ---- radix select: 3 passes of 8 bits on low-24 key bits ----
  unsigned int prefix = 0;
  int needed = 256;
  for (int pass = 0; pass < 3; ++pass) {
    int shift = 16 - 8 * pass;
    hist[tx] = 0u;
    __syncthreads();
    for (int i = tx; i < N; i += 256) {
      unsigned int v = sk[i];
      if (v != 0u) {
        unsigned int k24 = v & 0xFFFFFFu;
        if (pass == 0 || (k24 >> (shift + 8)) == prefix)
          atomicAdd(&hist[(k24 >> shift) & 255u], 1u);
      }
    }
    __syncthreads();
    unsigned int S = 0;
    for (int b = 0; b < 256; ++b) {
      unsigned int h = hist[b];
      S += (b >= tx) ? h : 0u;
    }
    if (pass == 0 && tx == 0) sh_V = (int)S;
    __syncthreads();
    if (pass == 0) needed = (sh_V < 256) ? sh_V : 256;
    if (sh_V > 0) {
      int Snext = (int)S - (int)hist[tx];
      if ((int)S >= needed && Snext < needed) { sh_digit = tx; sh_nextS = Snext; }
    }
    __syncthreads();
    if (sh_V > 0) {
      prefix = (prefix << 8) | (unsigned int)sh_digit;
      needed = needed - sh_nextS;
    }
    __syncthreads();
  }

  // ---- collect candidates (key24 >= prefix), build u64 keys ----
  if (tx == 0) scnt = 0;
  #pragma unroll
  for (int q = 0; q < 4; ++q) slist[tx + q * 256] = 0ull;
  __syncthreads();
  if (sh_V > 0) {
    for (int i = tx; i < N; i += 256) {
      unsigned int v = sk[i];
      if (v != 0u && (v & 0xFFFFFFu) >= prefix) {
        int p = atomicAdd(&scnt, 1);
        if (p < 1024)
          slist[p] = ((unsigned long long)v << 32) | (unsigned long long)(0xFFFFFFFFu - (unsigned)i);
      }
    }
  }
  __syncthreads();
  int M = scnt < 1024 ? scnt : 1024;

  // ---- rank sort (keys unique): sorted[rank] = key, keep top 256 ----
  skey64[tx] = 0ull;
  __syncthreads();
  for (int it = tx; it < M; it += 256) {
    unsigned long long K = slist[it];
    int rank = 0;
    for (int j = 0; j < M; ++j) rank += (slist[j] > K) ? 1 : 0;
    if (rank < 256) skey64[rank] = K;
  }
  __syncthreads();

  // ---- decode 256 slots ----
  {
    unsigned long long key = skey64[tx];
    float x1 = 0.f, y1 = 0.f, x2 = 0.f, y2 = 0.f, sc = 0.f;
    if (key != 0ull) {
      sc = __uint_as_float((unsigned int)(key >> 32));
      int idx = (int)(0xFFFFFFFFu - (unsigned int)(key & 0xFFFFFFFFull));
      decode_one(anch, tv, idx, x1, y1, x2, y2);
    }
    bx0[tx] = x1; bx1[tx] = y1; bx2[tx] = x2; bx3[tx] = y2;
    bsc[tx] = sc;
    bar[tx] = (x2 - x1 + 1.f) * (y2 - y1 + 1.f);
    unsigned long long b = __ballot(sc > 0.5f);
    if ((tx & 63) == 0) kinit[tx >> 6] = b;
  }
  __syncthreads();

  // ---- suppression rows: bits j>i with IoU>0.3 ----
  {
    float xi1 = bx0[tx], yi1 = bx1[tx], xi2 = bx2[tx], yi2 = bx3[tx], ai = bar[tx];
    #pragma unroll
    for (int w = 0; w < 4; ++w) {
      unsigned long long rr = 0ull;
      int j0 = w * 64;
      int js = (tx + 1 > j0) ? (tx + 1) : j0;
      for (int j = js; j < j0 + 64; ++j) {
        float xx1 = fmaxf(xi1, bx0[j]);
        float yy1 = fmaxf(yi1, bx1[j]);
        float xx2 = fminf(xi2, bx2[j]);
        float yy2 = fminf(yi2, bx3[j]);
        float ww = fmaxf(0.f, xx2 - xx1 + 1.f);
        float hh = fmaxf(0.f, yy2 - yy1 + 1.f);
        float inter = ww * hh;
        float ovr = inter / (ai + bar[j] - inter);
        rr |= (ovr > 0.3f) ? (1ull << (j & 63)) : 0ull;
      }
      rsup[tx][w] = rr;
    }
  }
  __syncthreads();

  // ---- greedy propagation (single thread, branchless bitmask) ----
  if (tx == 0) {
    unsigned long long k0 = kinit[0], k1 = kinit[1], k2 = kinit[2], k3 = kinit[3];
    #define NMS_CHUNK(W, KW) \
      for (int i = W * 64; i < W * 64 + 64; ++i) { \
        unsigned long long live = 0ull - ((KW >> (i & 63)) & 1ull); \
        k0 &= ~(rsup[i][0] & live); \
        k1 &= ~(rsup[i][1] & live); \
        k2 &= ~(rsup[i][2] & live); \
        k3 &= ~(rsup[i][3] & live); \
      }
    NMS_CHUNK(0, k0)
    NMS_CHUNK(1, k1)
    NMS_CHUNK(2, k2)
    NMS_CHUNK(3, k3)
    #undef NMS_CHUNK
    kfin[0] = k0; kfin[1] = k1; kfin[2] = k2; kfin[3] = k3;
  }
  __syncthreads();
  bkeepArr[tx] = (unsigned char)((kfin[tx >> 6] >> (tx & 63)) & 1ull);
  __syncthreads();

  // ---- stable order: kept first, take 32 ----
  if (tx == 0) {
    int s = 0;
    for (int r = 0; r < 256 && s < 32; ++r) if (bkeepArr[r]) sel[s++] = r;
    for (int r = 0; r < 256 && s < 32; ++r) if (!bkeepArr[r]) sel[s++] = r;
  }
  __syncthreads();
  if (tx < 32) {
    int r = sel[tx];
    int m = bkeepArr[r];
    int ob = (img * 3 + lvl) * 32 + tx;
    float d0 = 0.f, d1 = 0.f, d2 = 0.f, d3 = 0.f, d4 = 0.f;
    int c0 = 0, c1 = 0, c2 = 2, c3 = 2;
    if (m) {
      d0 = bx0[r]; d1 = bx1[r]; d2 = bx2[r]; d3 = bx3[r]; d4 = bsc[r];
      c0 = ((int)d0) / stride; c1 = ((int)d1) / stride;
      c2 = ((int)d2) / stride; c3 = ((int)d3) / stride;
    }
    dout[ob * 5 + 0] = d0; dout[ob * 5 + 1] = d1; dout[ob * 5 + 2] = d2;
    dout[ob * 5 + 3] = d3; dout[ob * 5 + 4] = d4;
    dout[960 + ob] = m ? 1.f : 0.f;
    coords[ob * 5 + 0] = c0; coords[ob * 5 + 1] = c1;
    coords[ob * 5 + 2] = c2; coords[ob * 5 + 3] = c3;
    coords[ob * 5 + 4] = m;
  }
}

// ---------------- ROI adaptive 7x7 maxpool (reads fp16 H/L HWC, reconstructs) ----------------
__global__ __launch_bounds__(256) void roipool_kernel(
    const _Float16* __restrict__ fh0, const _Float16* __restrict__ fl0,
    const _Float16* __restrict__ fh1, const _Float16* __restrict__ fl1,
    const _Float16* __restrict__ fh2, const _Float16* __restrict__ fl2,
    const int* __restrict__ coords, float* __restrict__ dout)
{
  int slot = blockIdx.x, lvl = blockIdx.y, img = blockIdx.z;
  int ob = (img * 3 + lvl) * 32 + slot;
  int c = threadIdx.x;
  const int* cw = coords + ob * 5;
  float* outp = dout + 1152 + (size_t)ob * 256 * 49 + (size_t)c * 49;
  int m = cw[4];
  if (!m) {
    #pragma unroll
    for (int i = 0; i < 49; ++i) outp[i] = 0.f;
    return;
  }
  int H = (lvl == 0) ? 64 : ((lvl == 1) ? 32 : 16);
  const _Float16* fh = ((lvl == 0) ? fh0 : ((lvl == 1) ? fh1 : fh2)) + (size_t)img * H * H * 256;
  const _Float16* fl = ((lvl == 0) ? fl0 : ((lvl == 1) ? fl1 : fl2)) + (size_t)img * H * H * 256;
  int lox = cw[0], loy = cw[1], hix = cw[2], hiy = cw[3];
  int Lx = hix - lox, Ly = hiy - loy;
  for (int yi = 0; yi < 7; ++yi) {
    int ys = loy + (yi * Ly) / 7;
    int ye = loy + ((yi + 1) * Ly + 6) / 7;
    for (int xi = 0; xi < 7; ++xi) {
      int xs = lox + (xi * Lx) / 7;
      int xe = lox + ((xi + 1) * Lx + 6) / 7;
      float mx = -3.402823466e+38f;
      for (int y = ys; y < ye; ++y)
        for (int x = xs; x < xe; ++x) {
          size_t idx = ((size_t)y * H + x) * 256 + c;
          float v = (float)fh[idx] + (float)fl[idx] * (1.f / 4096.f);
          mx = fmaxf(mx, v);
        }
      outp[yi * 7 + xi] = mx;
    }
  }
}

// ---------------- host ----------------
extern "C" void kernel_launch(void* const* d_in, const int* in_sizes, int n_in,
                              void* d_out, int out_size, void* d_ws, size_t ws_size,
                              hipStream_t stream)
{
  (void)in_sizes; (void)n_in; (void)out_size; (void)ws_size;
  char* ws = (char*)d_ws;
  const float* layer2 = (const float*)d_in[0];
  const float* layer3 = (const float*)d_in[1];
  const float* layer4 = (const float*)d_in[2];
  const float* anch2  = (const float*)d_in[3];
  const float* anch3  = (const float*)d_in[4];
  const float* anch4  = (const float*)d_in[5];
  const float* hw1 = (const float*)d_in[6];
  const float* hg1 = (const float*)d_in[7];
  const float* hb1 = (const float*)d_in[8];
  const float* hm1 = (const float*)d_in[9];
  const float* hv1 = (const float*)d_in[10];
  const float* hw2 = (const float*)d_in[11];
  const float* hg2 = (const float*)d_in[12];
  const float* hb2 = (const float*)d_in[13];
  const float* hm2 = (const float*)d_in[14];
  const float* hv2 = (const float*)d_in[15];
  const float* clsw = (const float*)d_in[16];
  const float* locw = (const float*)d_in[17];
  float* dout = (float*)d_out;

  _Float16* i0H = (_Float16*)(ws + OFF_I0H);
  _Float16* i0L = (_Float16*)(ws + OFF_I0L);
  _Float16* i1H = (_Float16*)(ws + OFF_I1H);
  _Float16* i1L = (_Float16*)(ws + OFF_I1L);
  _Float16* i2H = (_Float16*)(ws + OFF_I2H);
  _Float16* i2L = (_Float16*)(ws + OFF_I2L);
  float* l3f = (float*)(ws + OFF_L3F);
  _Float16* h0H = (_Float16*)(ws + OFF_H0H);
  _Float16* h0L = (_Float16*)(ws + OFF_H0L);
  _Float16* h1H = (_Float16*)(ws + OFF_H1H);
  _Float16* h1L = (_Float16*)(ws + OFF_H1L);
  _Float16* h2H = (_Float16*)(ws + OFF_H2H);
  _Float16* h2L = (_Float16*)(ws + OFF_H2L);
  float* logits = (float*)(ws + OFF_LOGITS);
  float* tvals  = (float*)(ws + OFF_TVALS);
  unsigned int* skey = (unsigned int*)(ws + OFF_SKEY);
  int* coords = (int*)(ws + OFF_COORDS);
  float* inv1  = (float*)(ws + OFF_LOGITS - 4096);  // reuse tail of H2L region? no -- use dedicated small slots below
  // small BN buffers: carve from the end of COORDS region (aligned, plenty of ws)
  float* bn = (float*)(ws + OFF_COORDS + 4096);
  inv1 = bn; float* beta1 = bn + 256; float* inv2 = bn + 512; float* beta2 = bn + 768;

  prep_bn_kernel<<<1, 256, 0, stream>>>(hg1, hb1, hm1, hv1, hg2, hb2, hm2, hv2,
                                        inv1, beta1, inv2, beta2);
  prep_w_kernel<<<2048, 256, 0, stream>>>(hw1, hw2, clsw, locw, ws);

  // FPN merges into fp16 H/L HWC (and l3 f32 CHW for the l2 merge)
  fuse_kernel<<<dim3(4, 2), 256, 0, stream>>>(layer4, nullptr, nullptr, i2H, i2L, 16, 4);
  fuse_kernel<<<dim3(16, 2), 256, 0, stream>>>(layer3, layer4, l3f, i1H, i1L, 32, 5);
  fuse_kernel<<<dim3(64, 2), 256, 0, stream>>>(layer2, l3f, nullptr, i0H, i0L, 64, 6);

  CArgs c1;
  c1.inH[0] = i0H; c1.inH[1] = i1H; c1.inH[2] = i2H;
  c1.inL[0] = i0L; c1.inL[1] = i1L; c1.inL[2] = i2L;
  c1.wH = (const _Float16*)(ws + OFF_W1H); c1.wL = (const _Float16*)(ws + OFF_W1L);
  c1.outH[0] = h0H; c1.outH[1] = h1H; c1.outH[2] = h2H;
  c1.outL[0] = h0L; c1.outL[1] = h1L; c1.outL[2] = h2L;
  c1.inv = inv1; c1.beta = beta1;
  c1.logits = nullptr; c1.tvals = nullptr;
  c1.ocw = 256; c1.mode = 0;
  conv_mfma_kernel<2><<<dim3(84, 4, 2), 64, 0, stream>>>(c1);

  // conv2 out aliases I-space (dead after conv1)
  _Float16* f0H = i0H; _Float16* f0L = i0L;
  _Float16* f1H = i1H; _Float16* f1L = i1L;
  _Float16* f2H = i2H; _Float16* f2L = i2L;

  CArgs c2;
  c2.inH[0] = h0H; c2.inH[1] = h1H; c2.inH[2] = h2H;
  c2.inL[0] = h0L; c2.inL[1] = h1L; c2.inL[2] = h2L;
  c2.wH = (const _Float16*)(ws + OFF_W2H); c2.wL = (const _Float16*)(ws + OFF_W2L);
  c2.outH[0] = f0H; c2.outH[1] = f1H; c2.outH[2] = f2H;
  c2.outL[0] = f0L; c2.outL[1] = f1L; c2.outL[2] = f2L;
  c2.inv = inv2; c2.beta = beta2;
  c2.logits = nullptr; c2.tvals = nullptr;
  c2.ocw = 256; c2.mode = 0;
  conv_mfma_kernel<2><<<dim3(84, 4, 2), 64, 0, stream>>>(c2);

  CArgs cr;
  cr.inH[0] = f0H; cr.inH[1] = f1H; cr.inH[2] = f2H;
  cr.inL[0] = f0L; cr.inL[1] = f1L; cr.inL[2] = f2L;
  cr.wH = (const _Float16*)(ws + OFF_WRH); cr.wL = (const _Float16*)(ws + OFF_WRL);
  cr.outH[0] = nullptr; cr.outH[1] = nullptr; cr.outH[2] = nullptr;
  cr.outL[0] = nullptr; cr.outL[1] = nullptr; cr.outL[2] = nullptr;
  cr.inv = nullptr; cr.beta = nullptr;
  cr.logits = logits; cr.tvals = tvals;
  cr.ocw = 32; cr.mode = 2;
  conv_mfma_kernel<1><<<dim3(84, 1, 2), 64, 0, stream>>>(cr);

  score_kernel<<<126, 256, 0, stream>>>(logits, tvals, anch2, anch3, anch4, skey);
  postproc_kernel<<<dim3(3, 2), 256, 0, stream>>>(tvals, anch2, anch3, anch4, skey, dout, coords);
  roipool_kernel<<<dim3(32, 3, 2), 256, 0, stream>>>(f0H, f0L, f1H, f1L, f2H, f2L, coords, dout);
}

// Round 5
// 432.382 us; speedup vs baseline: 2.6724x; 1.2389x over previous
//
#include <hip/hip_runtime.h>
#include <math.h>

typedef __attribute__((ext_vector_type(8))) _Float16 f16x8;
typedef __attribute__((ext_vector_type(16))) float f32x16;
typedef __attribute__((ext_vector_type(4))) float float4v;

// ---------------- fp16 split2 helpers: v = h + l/4096 ----------------
__device__ __forceinline__ void split2(float v, _Float16& h, _Float16& l) {
  h = (_Float16)v;
  l = (_Float16)((v - (float)h) * 4096.0f);
}

// ---------------- workspace layout (byte offsets) ----------------
#define OFF_W1H  0UL          // 9*256*256*2 = 1179648
#define OFF_W1L  1179648UL
#define OFF_W2H  2359296UL
#define OFF_W2L  3538944UL
#define OFF_WRH  4718592UL    // 9*32*256*2 = 147456
#define OFF_WRL  4866048UL
#define OFF_I0H  5013504UL    // 2*4096*256*2 = 4194304  (aliased as conv2-out F after conv1)
#define OFF_I0L  9207808UL
#define OFF_I1H  13402112UL   // 2*1024*256*2 = 1048576
#define OFF_I1L  14450688UL
#define OFF_I2H  15499264UL   // 2*256*256*2 = 262144
#define OFF_I2L  15761408UL
#define OFF_L3F  16023552UL   // f32 CHW 2*256*1024*4 = 2097152
#define OFF_H0H  18120704UL
#define OFF_H0L  22315008UL
#define OFF_H1H  26509312UL
#define OFF_H1L  27557888UL
#define OFF_H2H  28606464UL
#define OFF_H2L  28868608UL
#define OFF_LOGITS 29130752UL // 2*16128*4 = 129024
#define OFF_TVALS  29259776UL // 516096
#define OFF_SKEY   29775872UL // 129024
#define OFF_COORDS 29904896UL // 3840
// total ~29.9 MB

// out layout: dets[2][3][32][5] @0 (960) | mask[2][3][32] @960 (192) | rois @1152

// ---------------- prep: BN fold ----------------
__global__ __launch_bounds__(256) void prep_bn_kernel(
    const float* __restrict__ hg1, const float* __restrict__ hb1,
    const float* __restrict__ hm1, const float* __restrict__ hv1,
    const float* __restrict__ hg2, const float* __restrict__ hb2,
    const float* __restrict__ hm2, const float* __restrict__ hv2,
    float* __restrict__ inv1, float* __restrict__ beta1,
    float* __restrict__ inv2, float* __restrict__ beta2)
{
  int t = threadIdx.x;
  float i1 = (float)((double)hg1[t] / sqrt((double)hv1[t] + 1e-5));
  inv1[t] = i1;
  beta1[t] = hb1[t] - hm1[t] * i1;
  float i2 = (float)((double)hg2[t] / sqrt((double)hv2[t] + 1e-5));
  inv2[t] = i2;
  beta2[t] = hb2[t] - hm2[t] * i2;
}

// ---------------- prep: weight split into [dydx][oc][ic] fp16 H/L ----------------
#define L1SZ 589824   // 9*256*256
#define RPNSZ 73728   // 9*32*256
__global__ __launch_bounds__(256) void prep_w_kernel(
    const float* __restrict__ hw1, const float* __restrict__ hw2,
    const float* __restrict__ clsw, const float* __restrict__ locw,
    char* __restrict__ ws)
{
  _Float16* w1h = (_Float16*)(ws + OFF_W1H);
  _Float16* w1l = (_Float16*)(ws + OFF_W1L);
  _Float16* w2h = (_Float16*)(ws + OFF_W2H);
  _Float16* w2l = (_Float16*)(ws + OFF_W2L);
  _Float16* wrh = (_Float16*)(ws + OFF_WRH);
  _Float16* wrl = (_Float16*)(ws + OFF_WRL);
  const int TOT = 2 * L1SZ + RPNSZ;
  for (int e = blockIdx.x * 256 + threadIdx.x; e < TOT; e += gridDim.x * 256) {
    float val; _Float16 *dh, *dl; int di;
    if (e < L1SZ) {
      int dydx = e >> 16, oc = (e >> 8) & 255, ic = e & 255;
      val = hw1[(size_t)(oc * 256 + ic) * 9 + dydx];
      dh = w1h; dl = w1l; di = e;
    } else if (e < 2 * L1SZ) {
      int e2 = e - L1SZ;
      int dydx = e2 >> 16, oc = (e2 >> 8) & 255, ic = e2 & 255;
      val = hw2[(size_t)(oc * 256 + ic) * 9 + dydx];
      dh = w2h; dl = w2l; di = e2;
    } else {
      int e3 = e - 2 * L1SZ;
      int dydx = e3 >> 13, oc = (e3 >> 8) & 31, ic = e3 & 255;
      if (oc < 3) val = clsw[(size_t)(oc * 256 + ic) * 9 + dydx];
      else if (oc < 15) val = locw[(size_t)((oc - 3) * 256 + ic) * 9 + dydx];
      else val = 0.f;
      dh = wrh; dl = wrl; di = e3;
    }
    _Float16 h, l;
    split2(val, h, l);
    dh[di] = h; dl[di] = l;
  }
}

// ---------------- fuse: hwc_f16(H,L) = a_chw + upsample2x(b_chw); optional f32 CHW copy ----------------
__global__ __launch_bounds__(256) void fuse_kernel(
    const float* __restrict__ a, const float* __restrict__ bUp,
    float* __restrict__ f32chw, _Float16* __restrict__ oH, _Float16* __restrict__ oL,
    int H, int logW)
{
  __shared__ float T[32][65];
  int HW = H * H;
  int img = blockIdx.y;
  const float* ap = a + (size_t)img * 256 * HW;
  const float* bp = bUp ? (bUp + (size_t)img * 256 * (HW >> 2)) : nullptr;
  float* fp = f32chw ? (f32chw + (size_t)img * 256 * HW) : nullptr;
  _Float16* oHp = oH + (size_t)img * HW * 256;
  _Float16* oLp = oL + (size_t)img * HW * 256;
  int p0 = blockIdx.x * 64;
  int tid = threadIdx.x;
  int px = tid & 63, cg = tid >> 6;
  int gp = p0 + px;
  int y = gp >> logW, x = gp & (H - 1);
  int px2 = tid >> 2, q = tid & 3;
  for (int c0 = 0; c0 < 256; c0 += 32) {
    #pragma unroll
    for (int cc = 0; cc < 8; ++cc) {
      int c = c0 + cg * 8 + cc;
      float v = ap[(size_t)c * HW + gp];
      if (bp) v += bp[(size_t)c * (HW >> 2) + (y >> 1) * (H >> 1) + (x >> 1)];
      if (fp) fp[(size_t)c * HW + gp] = v;
      T[cg * 8 + cc][px] = v;
    }
    __syncthreads();
    {
      size_t oa = (size_t)(p0 + px2) * 256 + c0 + q * 8;
      f16x8 hs, ls;
      #pragma unroll
      for (int j = 0; j < 8; ++j) {
        float v = T[q * 8 + j][px2];
        _Float16 h, l;
        split2(v, h, l);
        hs[j] = h; ls[j] = l;
      }
      *(f16x8*)&oHp[oa] = hs;
      *(f16x8*)&oLp[oa] = ls;
    }
    __syncthreads();
  }
}

// ---------------- MFMA implicit-GEMM 3x3 conv: 1 wave/block, 64px x (NSUB*32)oc ----------------
struct CArgs {
  const _Float16* inH[3]; const _Float16* inL[3];   // fp16 HWC per level
  const _Float16* wH; const _Float16* wL;           // [9][ocw][256]
  _Float16* outH[3]; _Float16* outL[3];             // fp16 HWC outs (mode 0)
  const float* inv; const float* beta;              // BN folded
  float* logits; float* tvals;                      // mode 2
  int ocw; int mode;                                // 0 head, 2 rpn
};

template<int NSUB>
__global__ __launch_bounds__(64) void conv_mfma_kernel(CArgs a)
{
  __shared__ _Float16 Ph[100 * 40], Pl[100 * 40];   // 16000 B

  int bt = blockIdx.x;
  int lvl, tile;
  if (bt < 64) { lvl = 0; tile = bt; }
  else if (bt < 80) { lvl = 1; tile = bt - 64; }
  else { lvl = 2; tile = bt - 80; }
  int H = (lvl == 0) ? 64 : ((lvl == 1) ? 32 : 16);
  int HW = H * H;
  int tpr = H >> 3;
  int ty0 = (tile / tpr) * 8, tx0 = (tile % tpr) * 8;
  int img = blockIdx.z;
  int ocb = blockIdx.y * 64;
  const _Float16* inH = a.inH[lvl] + (size_t)img * HW * 256;
  const _Float16* inL = a.inL[lvl] + (size_t)img * HW * 256;

  int lane = threadIdx.x;
  int row = lane & 31, khalf = lane >> 5;

  f32x16 acc1[2][NSUB];   // h*h
  f32x16 acc2[2][NSUB];   // h*l' + l'*h  (scaled by 4096)
  #pragma unroll
  for (int ms = 0; ms < 2; ++ms)
    #pragma unroll
    for (int os = 0; os < NSUB; ++os)
      #pragma unroll
      for (int j = 0; j < 16; ++j) { acc1[ms][os][j] = 0.f; acc2[ms][os][j] = 0.f; }

  // A-read base offsets (per m-subtile; dydx offset added in loop)
  int aoff[2];
  #pragma unroll
  for (int ms = 0; ms < 2; ++ms) {
    int m = ms * 32 + row;
    aoff[ms] = ((m >> 3) * 10 + (m & 7)) * 40 + khalf * 8;
  }

  for (int icb = 0; icb < 8; ++icb) {
    // ---- stage 10x10x32 patch (H,L) ----
    for (int u = lane; u < 400; u += 64) {
      int pxl = u >> 2, icq = u & 3;
      int py = pxl / 10, pxx = pxl - py * 10;
      int gy = ty0 + py - 1, gx = tx0 + pxx - 1;
      int lo = pxl * 40 + icq * 8;
      if ((unsigned)gy < (unsigned)H && (unsigned)gx < (unsigned)H) {
        size_t ga = (size_t)(gy * H + gx) * 256 + icb * 32 + icq * 8;
        *(f16x8*)&Ph[lo] = *(const f16x8*)&inH[ga];
        *(f16x8*)&Pl[lo] = *(const f16x8*)&inL[ga];
      } else {
        f16x8 z;
        #pragma unroll
        for (int j = 0; j < 8; ++j) z[j] = (_Float16)0.f;
        *(f16x8*)&Ph[lo] = z;
        *(f16x8*)&Pl[lo] = z;
      }
    }
    __syncthreads();

    for (int dydx = 0; dydx < 9; ++dydx) {
      int dy = dydx / 3, dx = dydx - dy * 3;
      int pshift = (dy * 10 + dx) * 40;
      #pragma unroll
      for (int k2 = 0; k2 < 2; ++k2) {
        // B frags from global (L2-resident), layout matches lanes exactly
        f16x8 bh[NSUB], bl[NSUB];
        #pragma unroll
        for (int os = 0; os < NSUB; ++os) {
          size_t ga = ((size_t)(dydx * a.ocw) + ocb + os * 32 + row) * 256
                      + icb * 32 + k2 * 16 + khalf * 8;
          bh[os] = *(const f16x8*)&a.wH[ga];
          bl[os] = *(const f16x8*)&a.wL[ga];
        }
        // A frags from LDS
        f16x8 ah[2], al[2];
        #pragma unroll
        for (int ms = 0; ms < 2; ++ms) {
          int off = aoff[ms] + pshift + k2 * 16;
          ah[ms] = *(const f16x8*)&Ph[off];
          al[ms] = *(const f16x8*)&Pl[off];
        }
        #pragma unroll
        for (int ms = 0; ms < 2; ++ms)
          #pragma unroll
          for (int os = 0; os < NSUB; ++os) {
            acc1[ms][os] = __builtin_amdgcn_mfma_f32_32x32x16_f16(ah[ms], bh[os], acc1[ms][os], 0, 0, 0);
            acc2[ms][os] = __builtin_amdgcn_mfma_f32_32x32x16_f16(ah[ms], bl[os], acc2[ms][os], 0, 0, 0);
            acc2[ms][os] = __builtin_amdgcn_mfma_f32_32x32x16_f16(al[ms], bh[os], acc2[ms][os], 0, 0, 0);
          }
      }
    }
    __syncthreads();
  }

  // ---- epilogue ----
  if (a.mode == 0) {
    _Float16* outH = a.outH[lvl] + (size_t)img * HW * 256;
    _Float16* outL = a.outL[lvl] + (size_t)img * HW * 256;
    #pragma unroll
    for (int ms = 0; ms < 2; ++ms)
      #pragma unroll
      for (int os = 0; os < NSUB; ++os) {
        int oc = ocb + os * 32 + row;
        float iv = a.inv[oc], bb = a.beta[oc];
        #pragma unroll
        for (int r = 0; r < 16; ++r) {
          int ml = (r & 3) + 8 * (r >> 2) + 4 * khalf;
          int m = ms * 32 + ml;
          int y = ty0 + (m >> 3), x = tx0 + (m & 7);
          float v = acc1[ms][os][r] + acc2[ms][os][r] * (1.f / 4096.f);
          v = v * iv + bb;
          v = (v >= 0.f) ? v : 0.01f * v;
          _Float16 h, l;
          split2(v, h, l);
          size_t oa = (size_t)(y * H + x) * 256 + oc;
          outH[oa] = h;
          outL[oa] = l;
        }
      }
  } else {
    int oc = ocb + row;   // NSUB==1
    if (oc < 15) {
      int abase = (lvl == 0) ? 0 : ((lvl == 1) ? 12288 : 15360);
      #pragma unroll
      for (int ms = 0; ms < 2; ++ms)
        #pragma unroll
        for (int r = 0; r < 16; ++r) {
          int ml = (r & 3) + 8 * (r >> 2) + 4 * khalf;
          int m = ms * 32 + ml;
          int y = ty0 + (m >> 3), x = tx0 + (m & 7);
          int gi = img * 16128 + abase + (y * H + x) * 3;
          float v = acc1[ms][0][r] + acc2[ms][0][r] * (1.f / 4096.f);
          if (oc < 3) a.logits[gi + oc] = v;
          else { int r2 = oc - 3; a.tvals[(size_t)(gi + (r2 >> 2)) * 4 + (r2 & 3)] = v; }
        }
    }
  }
}

// ---------------- decode helper ----------------
__device__ __forceinline__ void decode_one(const float* __restrict__ anch,
                                           const float* __restrict__ tv, int i,
                                           float& x1, float& y1, float& x2, float& y2)
{
  float t0 = tv[i * 4 + 0], t1 = tv[i * 4 + 1], t2 = tv[i * 4 + 2], t3 = tv[i * 4 + 3];
  float a0 = anch[i * 4 + 0], a1 = anch[i * 4 + 1], a2 = anch[i * 4 + 2], a3 = anch[i * 4 + 3];
  float aw = a2 - a0, ah = a3 - a1;
  float xx = a0 + t0 * aw;
  float yy = a1 + t1 * ah;
  float bw = aw * expf(t2);
  float bh = ah * expf(t3);
  x1 = fminf(fmaxf(xx, 0.f), 512.f);
  y1 = fminf(fmaxf(yy, 0.f), 512.f);
  x2 = fminf(fmaxf(xx + bw, 0.f), 512.f);
  y2 = fminf(fmaxf(yy + bh, 0.f), 512.f);
}

// ---------------- score kernel ----------------
__global__ __launch_bounds__(256) void score_kernel(
    const float* __restrict__ logits, const float* __restrict__ tvals,
    const float* __restrict__ anch0, const float* __restrict__ anch1, const float* __restrict__ anch2,
    unsigned int* __restrict__ skey)
{
  int g = blockIdx.x * 256 + threadIdx.x;
  if (g >= 2 * 16128) return;
  int img = g / 16128, r = g - img * 16128;
  int lvl = (r < 12288) ? 0 : ((r < 15360) ? 1 : 2);
  int abase = (lvl == 0) ? 0 : ((lvl == 1) ? 12288 : 15360);
  int stride = (lvl == 0) ? 8 : ((lvl == 1) ? 16 : 32);
  const float* anch = (lvl == 0) ? anch0 : ((lvl == 1) ? anch1 : anch2);
  int i = r - abase;
  float lv = logits[g];
  float sc = 1.f / (1.f + expf(-lv));
  float x1, y1, x2, y2;
  decode_one(anch, tvals + (size_t)(img * 16128 + abase) * 4, i, x1, y1, x2, y2);
  float minsz = 2.0f * (float)stride;
  bool valid = (sc > 0.5f) && ((x2 - x1) >= minsz) && ((y2 - y1) >= minsz);
  skey[g] = valid ? __float_as_uint(sc) : 0u;
}

// ---------------- postproc: radix-select -> rank-sort -> bitmask NMS -> outputs ----------------
__global__ __launch_bounds__(256) void postproc_kernel(
    const float* __restrict__ tvals,
    const float* __restrict__ anch0, const float* __restrict__ anch1, const float* __restrict__ anch2,
    const unsigned int* __restrict__ skey, float* __restrict__ dout, int* __restrict__ coords)
{
  int lvl = blockIdx.x, img = blockIdx.y;
  int N = (lvl == 0) ? 12288 : ((lvl == 1) ? 3072 : 768);
  int stride = (lvl == 0) ? 8 : ((lvl == 1) ? 16 : 32);
  int abase = (lvl == 0) ? 0 : ((lvl == 1) ? 12288 : 15360);
  const float* anch = (lvl == 0) ? anch0 : ((lvl == 1) ? anch1 : anch2);
  const float* tv = tvals + (size_t)(img * 16128 + abase) * 4;
  const unsigned int* sk = skey + img * 16128 + abase;
  int tx = threadIdx.x;

  __shared__ unsigned int hist[256];
  __shared__ int sh_digit, sh_nextS, sh_V;
  __shared__ unsigned long long slist[1024];
  __shared__ int scnt;
  __shared__ unsigned long long skey64[256];
  __shared__ float bx0[256], bx1[256], bx2[256], bx3[256], bar[256], bsc[256];
  __shared__ unsigned long long rsup[256][4];
  __shared__ unsigned long long kinit[4], kfin[4];
  __shared__ unsigned char bkeepArr[256];
  __shared__ int sel[32];

  // ---- radix select: 3 passes of 8 bits on low-24 key bits ----
  unsigned int prefix = 0;
  int needed = 256;
  for (int pass = 0; pass < 3; ++pass) {
    int shift = 16 - 8 * pass;
    hist[tx] = 0u;
    __syncthreads();
    for (int i = tx; i < N; i += 256) {
      unsigned int v = sk[i];
      if (v != 0u) {
        unsigned int k24 = v & 0xFFFFFFu;
        if (pass == 0 || (k24 >> (shift + 8)) == prefix)
          atomicAdd(&hist[(k24 >> shift) & 255u], 1u);
      }
    }
    __syncthreads();
    unsigned int S = 0;
    for (int b = 0; b < 256; ++b) {
      unsigned int h = hist[b];
      S += (b >= tx) ? h : 0u;
    }
    if (pass == 0 && tx == 0) sh_V = (int)S;
    __syncthreads();
    if (pass == 0) needed = (sh_V < 256) ? sh_V : 256;
    if (sh_V > 0) {
      int Snext = (int)S - (int)hist[tx];
      if ((int)S >= needed && Snext < needed) { sh_digit = tx; sh_nextS = Snext; }
    }
    __syncthreads();
    if (sh_V > 0) {
      prefix = (prefix << 8) | (unsigned int)sh_digit;
      needed = needed - sh_nextS;
    }
    __syncthreads();
  }

  // ---- collect candidates (key24 >= prefix), build u64 keys ----
  if (tx == 0) scnt = 0;
  #pragma unroll
  for (int q = 0; q < 4; ++q) slist[tx + q * 256] = 0ull;
  __syncthreads();
  if (sh_V > 0) {
    for (int i = tx; i < N; i += 256) {
      unsigned int v = sk[i];
      if (v != 0u && (v & 0xFFFFFFu) >= prefix) {
        int p = atomicAdd(&scnt, 1);
        if (p < 1024)
          slist[p] = ((unsigned long long)v << 32) | (unsigned long long)(0xFFFFFFFFu - (unsigned)i);
      }
    }
  }
  __syncthreads();
  int M = scnt < 1024 ? scnt : 1024;

  // ---- rank sort (keys unique): sorted[rank] = key, keep top 256 ----
  skey64[tx] = 0ull;
  __syncthreads();
  for (int it = tx; it < M; it += 256) {
    unsigned long long K = slist[it];
    int rank = 0;
    for (int j = 0; j < M; ++j) rank += (slist[j] > K) ? 1 : 0;
    if (rank < 256) skey64[rank] = K;
  }
  __syncthreads();

  // ---- decode 256 slots ----
  {
    unsigned long long key = skey64[tx];
    float x1 = 0.f, y1 = 0.f, x2 = 0.f, y2 = 0.f, sc = 0.f;
    if (key != 0ull) {
      sc = __uint_as_float((unsigned int)(key >> 32));
      int idx = (int)(0xFFFFFFFFu - (unsigned int)(key & 0xFFFFFFFFull));
      decode_one(anch, tv, idx, x1, y1, x2, y2);
    }
    bx0[tx] = x1; bx1[tx] = y1; bx2[tx] = x2; bx3[tx] = y2;
    bsc[tx] = sc;
    bar[tx] = (x2 - x1 + 1.f) * (y2 - y1 + 1.f);
    unsigned long long b = __ballot(sc > 0.5f);
    if ((tx & 63) == 0) kinit[tx >> 6] = b;
  }
  __syncthreads();

  // ---- suppression rows: bits j>i with IoU>0.3 ----
  {
    float xi1 = bx0[tx], yi1 = bx1[tx], xi2 = bx2[tx], yi2 = bx3[tx], ai = bar[tx];
    #pragma unroll
    for (int w = 0; w < 4; ++w) {
      unsigned long long rr = 0ull;
      int j0 = w * 64;
      int js = (tx + 1 > j0) ? (tx + 1) : j0;
      for (int j = js; j < j0 + 64; ++j) {
        float xx1 = fmaxf(xi1, bx0[j]);
        float yy1 = fmaxf(yi1, bx1[j]);
        float xx2 = fminf(xi2, bx2[j]);
        float yy2 = fminf(yi2, bx3[j]);
        float ww = fmaxf(0.f, xx2 - xx1 + 1.f);
        float hh = fmaxf(0.f, yy2 - yy1 + 1.f);
        float inter = ww * hh;
        float ovr = inter / (ai + bar[j] - inter);
        rr |= (ovr > 0.3f) ? (1ull << (j & 63)) : 0ull;
      }
      rsup[tx][w] = rr;
    }
  }
  __syncthreads();

  // ---- greedy propagation (single thread, branchless bitmask) ----
  if (tx == 0) {
    unsigned long long k0 = kinit[0], k1 = kinit[1], k2 = kinit[2], k3 = kinit[3];
    #define NMS_CHUNK(W, KW) \
      for (int i = W * 64; i < W * 64 + 64; ++i) { \
        unsigned long long live = 0ull - ((KW >> (i & 63)) & 1ull); \
        k0 &= ~(rsup[i][0] & live); \
        k1 &= ~(rsup[i][1] & live); \
        k2 &= ~(rsup[i][2] & live); \
        k3 &= ~(rsup[i][3] & live); \
      }
    NMS_CHUNK(0, k0)
    NMS_CHUNK(1, k1)
    NMS_CHUNK(2, k2)
    NMS_CHUNK(3, k3)
    #undef NMS_CHUNK
    kfin[0] = k0; kfin[1] = k1; kfin[2] = k2; kfin[3] = k3;
  }
  __syncthreads();
  bkeepArr[tx] = (unsigned char)((kfin[tx >> 6] >> (tx & 63)) & 1ull);
  __syncthreads();

  // ---- stable order: kept first, take 32 ----
  if (tx == 0) {
    int s = 0;
    for (int r = 0; r < 256 && s < 32; ++r) if (bkeepArr[r]) sel[s++] = r;
    for (int r = 0; r < 256 && s < 32; ++r) if (!bkeepArr[r]) sel[s++] = r;
  }
  __syncthreads();
  if (tx < 32) {
    int r = sel[tx];
    int m = bkeepArr[r];
    int ob = (img * 3 + lvl) * 32 + tx;
    float d0 = 0.f, d1 = 0.f, d2 = 0.f, d3 = 0.f, d4 = 0.f;
    int c0 = 0, c1 = 0, c2 = 2, c3 = 2;
    if (m) {
      d0 = bx0[r]; d1 = bx1[r]; d2 = bx2[r]; d3 = bx3[r]; d4 = bsc[r];
      c0 = ((int)d0) / stride; c1 = ((int)d1) / stride;
      c2 = ((int)d2) / stride; c3 = ((int)d3) / stride;
    }
    dout[ob * 5 + 0] = d0; dout[ob * 5 + 1] = d1; dout[ob * 5 + 2] = d2;
    dout[ob * 5 + 3] = d3; dout[ob * 5 + 4] = d4;
    dout[960 + ob] = m ? 1.f : 0.f;
    coords[ob * 5 + 0] = c0; coords[ob * 5 + 1] = c1;
    coords[ob * 5 + 2] = c2; coords[ob * 5 + 3] = c3;
    coords[ob * 5 + 4] = m;
  }
}

// ---------------- ROI adaptive 7x7 maxpool: one block per (roi, bin) ----------------
// grid: x = slot*49 + bin, y = lvl, z = img; 256 threads = channels
__global__ __launch_bounds__(256) void roipool_kernel(
    const _Float16* __restrict__ fh0, const _Float16* __restrict__ fl0,
    const _Float16* __restrict__ fh1, const _Float16* __restrict__ fl1,
    const _Float16* __restrict__ fh2, const _Float16* __restrict__ fl2,
    const int* __restrict__ coords, float* __restrict__ dout)
{
  int bx = blockIdx.x;
  int slot = bx / 49, bin = bx - slot * 49;
  int yi = bin / 7, xi = bin - yi * 7;
  int lvl = blockIdx.y, img = blockIdx.z;
  int ob = (img * 3 + lvl) * 32 + slot;
  int c = threadIdx.x;
  const int* cw = coords + ob * 5;
  float* outp = dout + 1152 + (size_t)ob * 256 * 49 + (size_t)c * 49 + yi * 7 + xi;
  int m = cw[4];
  if (!m) { *outp = 0.f; return; }
  int H = (lvl == 0) ? 64 : ((lvl == 1) ? 32 : 16);
  const _Float16* fh = ((lvl == 0) ? fh0 : ((lvl == 1) ? fh1 : fh2)) + (size_t)img * H * H * 256;
  const _Float16* fl = ((lvl == 0) ? fl0 : ((lvl == 1) ? fl1 : fl2)) + (size_t)img * H * H * 256;
  int lox = cw[0], loy = cw[1], hix = cw[2], hiy = cw[3];
  int Lx = hix - lox, Ly = hiy - loy;
  int ys = loy + (yi * Ly) / 7;
  int ye = loy + ((yi + 1) * Ly + 6) / 7;
  int xs = lox + (xi * Lx) / 7;
  int xe = lox + ((xi + 1) * Lx + 6) / 7;
  float mx = -3.402823466e+38f;
  for (int y = ys; y < ye; ++y) {
    size_t rowb = ((size_t)y * H) * 256 + c;
    for (int x = xs; x < xe; ++x) {
      size_t idx = rowb + (size_t)x * 256;
      float v = (float)fh[idx] + (float)fl[idx] * (1.f / 4096.f);
      mx = fmaxf(mx, v);
    }
  }
  *outp = mx;
}

// ---------------- host ----------------
extern "C" void kernel_launch(void* const* d_in, const int* in_sizes, int n_in,
                              void* d_out, int out_size, void* d_ws, size_t ws_size,
                              hipStream_t stream)
{
  (void)in_sizes; (void)n_in; (void)out_size; (void)ws_size;
  char* ws = (char*)d_ws;
  const float* layer2 = (const float*)d_in[0];
  const float* layer3 = (const float*)d_in[1];
  const float* layer4 = (const float*)d_in[2];
  const float* anch2  = (const float*)d_in[3];
  const float* anch3  = (const float*)d_in[4];
  const float* anch4  = (const float*)d_in[5];
  const float* hw1 = (const float*)d_in[6];
  const float* hg1 = (const float*)d_in[7];
  const float* hb1 = (const float*)d_in[8];
  const float* hm1 = (const float*)d_in[9];
  const float* hv1 = (const float*)d_in[10];
  const float* hw2 = (const float*)d_in[11];
  const float* hg2 = (const float*)d_in[12];
  const float* hb2 = (const float*)d_in[13];
  const float* hm2 = (const float*)d_in[14];
  const float* hv2 = (const float*)d_in[15];
  const float* clsw = (const float*)d_in[16];
  const float* locw = (const float*)d_in[17];
  float* dout = (float*)d_out;

  _Float16* i0H = (_Float16*)(ws + OFF_I0H);
  _Float16* i0L = (_Float16*)(ws + OFF_I0L);
  _Float16* i1H = (_Float16*)(ws + OFF_I1H);
  _Float16* i1L = (_Float16*)(ws + OFF_I1L);
  _Float16* i2H = (_Float16*)(ws + OFF_I2H);
  _Float16* i2L = (_Float16*)(ws + OFF_I2L);
  float* l3f = (float*)(ws + OFF_L3F);
  _Float16* h0H = (_Float16*)(ws + OFF_H0H);
  _Float16* h0L = (_Float16*)(ws + OFF_H0L);
  _Float16* h1H = (_Float16*)(ws + OFF_H1H);
  _Float16* h1L = (_Float16*)(ws + OFF_H1L);
  _Float16* h2H = (_Float16*)(ws + OFF_H2H);
  _Float16* h2L = (_Float16*)(ws + OFF_H2L);
  float* logits = (float*)(ws + OFF_LOGITS);
  float* tvals  = (float*)(ws + OFF_TVALS);
  unsigned int* skey = (unsigned int*)(ws + OFF_SKEY);
  int* coords = (int*)(ws + OFF_COORDS);
  float* bn = (float*)(ws + OFF_COORDS + 4096);
  float* inv1 = bn; float* beta1 = bn + 256; float* inv2 = bn + 512; float* beta2 = bn + 768;

  prep_bn_kernel<<<1, 256, 0, stream>>>(hg1, hb1, hm1, hv1, hg2, hb2, hm2, hv2,
                                        inv1, beta1, inv2, beta2);
  prep_w_kernel<<<2048, 256, 0, stream>>>(hw1, hw2, clsw, locw, ws);

  // FPN merges into fp16 H/L HWC (and l3 f32 CHW for the l2 merge)
  fuse_kernel<<<dim3(4, 2), 256, 0, stream>>>(layer4, nullptr, nullptr, i2H, i2L, 16, 4);
  fuse_kernel<<<dim3(16, 2), 256, 0, stream>>>(layer3, layer4, l3f, i1H, i1L, 32, 5);
  fuse_kernel<<<dim3(64, 2), 256, 0, stream>>>(layer2, l3f, nullptr, i0H, i0L, 64, 6);

  CArgs c1;
  c1.inH[0] = i0H; c1.inH[1] = i1H; c1.inH[2] = i2H;
  c1.inL[0] = i0L; c1.inL[1] = i1L; c1.inL[2] = i2L;
  c1.wH = (const _Float16*)(ws + OFF_W1H); c1.wL = (const _Float16*)(ws + OFF_W1L);
  c1.outH[0] = h0H; c1.outH[1] = h1H; c1.outH[2] = h2H;
  c1.outL[0] = h0L; c1.outL[1] = h1L; c1.outL[2] = h2L;
  c1.inv = inv1; c1.beta = beta1;
  c1.logits = nullptr; c1.tvals = nullptr;
  c1.ocw = 256; c1.mode = 0;
  conv_mfma_kernel<2><<<dim3(84, 4, 2), 64, 0, stream>>>(c1);

  // conv2 out aliases I-space (dead after conv1)
  _Float16* f0H = i0H; _Float16* f0L = i0L;
  _Float16* f1H = i1H; _Float16* f1L = i1L;
  _Float16* f2H = i2H; _Float16* f2L = i2L;

  CArgs c2;
  c2.inH[0] = h0H; c2.inH[1] = h1H; c2.inH[2] = h2H;
  c2.inL[0] = h0L; c2.inL[1] = h1L; c2.inL[2] = h2L;
  c2.wH = (const _Float16*)(ws + OFF_W2H); c2.wL = (const _Float16*)(ws + OFF_W2L);
  c2.outH[0] = f0H; c2.outH[1] = f1H; c2.outH[2] = f2H;
  c2.outL[0] = f0L; c2.outL[1] = f1L; c2.outL[2] = f2L;
  c2.inv = inv2; c2.beta = beta2;
  c2.logits = nullptr; c2.tvals = nullptr;
  c2.ocw = 256; c2.mode = 0;
  conv_mfma_kernel<2><<<dim3(84, 4, 2), 64, 0, stream>>>(c2);

  CArgs cr;
  cr.inH[0] = f0H; cr.inH[1] = f1H; cr.inH[2] = f2H;
  cr.inL[0] = f0L; cr.inL[1] = f1L; cr.inL[2] = f2L;
  cr.wH = (const _Float16*)(ws + OFF_WRH); cr.wL = (const _Float16*)(ws + OFF_WRL);
  cr.outH[0] = nullptr; cr.outH[1] = nullptr; cr.outH[2] = nullptr;
  cr.outL[0] = nullptr; cr.outL[1] = nullptr; cr.outL[2] = nullptr;
  cr.inv = nullptr; cr.beta = nullptr;
  cr.logits = logits; cr.tvals = tvals;
  cr.ocw = 32; cr.mode = 2;
  conv_mfma_kernel<1><<<dim3(84, 1, 2), 64, 0, stream>>>(cr);

  score_kernel<<<126, 256, 0, stream>>>(logits, tvals, anch2, anch3, anch4, skey);
  postproc_kernel<<<dim3(3, 2), 256, 0, stream>>>(tvals, anch2, anch3, anch4, skey, dout, coords);
  roipool_kernel<<<dim3(32 * 49, 3, 2), 256, 0, stream>>>(f0H, f0L, f1H, f1L, f2H, f2L, coords, dout);
}

// Round 6
// 410.610 us; speedup vs baseline: 2.8141x; 1.0530x over previous
//
#include <hip/hip_runtime.h>
#include <math.h>

typedef __attribute__((ext_vector_type(8))) _Float16 f16x8;
typedef __attribute__((ext_vector_type(16))) float f32x16;
typedef unsigned long long ull;

// ---------------- fp16 split2 helpers: v = h + l/4096 ----------------
__device__ __forceinline__ void split2(float v, _Float16& h, _Float16& l) {
  h = (_Float16)v;
  l = (_Float16)((v - (float)h) * 4096.0f);
}

// ---------------- workspace layout (byte offsets) ----------------
#define OFF_W1H  0UL          // 9*256*256*2 = 1179648
#define OFF_W1L  1179648UL
#define OFF_W2H  2359296UL
#define OFF_W2L  3538944UL
#define OFF_WRH  4718592UL    // 9*32*256*2 = 147456
#define OFF_WRL  4866048UL
#define OFF_I0H  5013504UL    // 2*4096*256*2 = 4194304  (aliased as conv2-out F after conv1)
#define OFF_I0L  9207808UL
#define OFF_I1H  13402112UL
#define OFF_I1L  14450688UL
#define OFF_I2H  15499264UL
#define OFF_I2L  15761408UL
#define OFF_L3F  16023552UL   // f32 CHW 2*256*1024*4 = 2097152
#define OFF_H0H  18120704UL
#define OFF_H0L  22315008UL
#define OFF_H1H  26509312UL
#define OFF_H1L  27557888UL
#define OFF_H2H  28606464UL
#define OFF_H2L  28868608UL
#define OFF_LOGITS 29130752UL // 2*16128*4 = 129024
#define OFF_TVALS  29259776UL // 516096
#define OFF_SKEY   29775872UL // 129024
#define OFF_COORDS 29904896UL // 3840
#define OFF_BN     29908992UL // 4096
#define OFF_HIST   29917184UL // 6*2048*4 = 49152
// total ~30.0 MB

// out layout: dets[2][3][32][5] @0 (960) | mask[2][3][32] @960 (192) | rois @1152

// ---------------- prep: BN fold ----------------
__global__ __launch_bounds__(256) void prep_bn_kernel(
    const float* __restrict__ hg1, const float* __restrict__ hb1,
    const float* __restrict__ hm1, const float* __restrict__ hv1,
    const float* __restrict__ hg2, const float* __restrict__ hb2,
    const float* __restrict__ hm2, const float* __restrict__ hv2,
    float* __restrict__ inv1, float* __restrict__ beta1,
    float* __restrict__ inv2, float* __restrict__ beta2)
{
  int t = threadIdx.x;
  float i1 = (float)((double)hg1[t] / sqrt((double)hv1[t] + 1e-5));
  inv1[t] = i1;
  beta1[t] = hb1[t] - hm1[t] * i1;
  float i2 = (float)((double)hg2[t] / sqrt((double)hv2[t] + 1e-5));
  inv2[t] = i2;
  beta2[t] = hb2[t] - hm2[t] * i2;
}

// ---------------- zero hist ----------------
__global__ __launch_bounds__(256) void zero_hist_kernel(unsigned int* __restrict__ hist)
{
  hist[blockIdx.x * 256 + threadIdx.x] = 0u;
}

// ---------------- prep: weight split into [dydx][oc][ic] fp16 H/L ----------------
#define L1SZ 589824   // 9*256*256
#define RPNSZ 73728   // 9*32*256
__global__ __launch_bounds__(256) void prep_w_kernel(
    const float* __restrict__ hw1, const float* __restrict__ hw2,
    const float* __restrict__ clsw, const float* __restrict__ locw,
    char* __restrict__ ws)
{
  _Float16* w1h = (_Float16*)(ws + OFF_W1H);
  _Float16* w1l = (_Float16*)(ws + OFF_W1L);
  _Float16* w2h = (_Float16*)(ws + OFF_W2H);
  _Float16* w2l = (_Float16*)(ws + OFF_W2L);
  _Float16* wrh = (_Float16*)(ws + OFF_WRH);
  _Float16* wrl = (_Float16*)(ws + OFF_WRL);
  const int TOT = 2 * L1SZ + RPNSZ;
  for (int e = blockIdx.x * 256 + threadIdx.x; e < TOT; e += gridDim.x * 256) {
    float val; _Float16 *dh, *dl; int di;
    if (e < L1SZ) {
      int dydx = e >> 16, oc = (e >> 8) & 255, ic = e & 255;
      val = hw1[(size_t)(oc * 256 + ic) * 9 + dydx];
      dh = w1h; dl = w1l; di = e;
    } else if (e < 2 * L1SZ) {
      int e2 = e - L1SZ;
      int dydx = e2 >> 16, oc = (e2 >> 8) & 255, ic = e2 & 255;
      val = hw2[(size_t)(oc * 256 + ic) * 9 + dydx];
      dh = w2h; dl = w2l; di = e2;
    } else {
      int e3 = e - 2 * L1SZ;
      int dydx = e3 >> 13, oc = (e3 >> 8) & 31, ic = e3 & 255;
      if (oc < 3) val = clsw[(size_t)(oc * 256 + ic) * 9 + dydx];
      else if (oc < 15) val = locw[(size_t)((oc - 3) * 256 + ic) * 9 + dydx];
      else val = 0.f;
      dh = wrh; dl = wrl; di = e3;
    }
    _Float16 h, l;
    split2(val, h, l);
    dh[di] = h; dl[di] = l;
  }
}

// ---------------- fuse: hwc_f16(H,L) = a_chw + upsample2x(b_chw); optional f32 CHW copy ----------------
__global__ __launch_bounds__(256) void fuse_kernel(
    const float* __restrict__ a, const float* __restrict__ bUp,
    float* __restrict__ f32chw, _Float16* __restrict__ oH, _Float16* __restrict__ oL,
    int H, int logW)
{
  __shared__ float T[32][65];
  int HW = H * H;
  int img = blockIdx.y;
  const float* ap = a + (size_t)img * 256 * HW;
  const float* bp = bUp ? (bUp + (size_t)img * 256 * (HW >> 2)) : nullptr;
  float* fp = f32chw ? (f32chw + (size_t)img * 256 * HW) : nullptr;
  _Float16* oHp = oH + (size_t)img * HW * 256;
  _Float16* oLp = oL + (size_t)img * HW * 256;
  int p0 = blockIdx.x * 64;
  int tid = threadIdx.x;
  int px = tid & 63, cg = tid >> 6;
  int gp = p0 + px;
  int y = gp >> logW, x = gp & (H - 1);
  int px2 = tid >> 2, q = tid & 3;
  for (int c0 = 0; c0 < 256; c0 += 32) {
    #pragma unroll
    for (int cc = 0; cc < 8; ++cc) {
      int c = c0 + cg * 8 + cc;
      float v = ap[(size_t)c * HW + gp];
      if (bp) v += bp[(size_t)c * (HW >> 2) + (y >> 1) * (H >> 1) + (x >> 1)];
      if (fp) fp[(size_t)c * HW + gp] = v;
      T[cg * 8 + cc][px] = v;
    }
    __syncthreads();
    {
      size_t oa = (size_t)(p0 + px2) * 256 + c0 + q * 8;
      f16x8 hs, ls;
      #pragma unroll
      for (int j = 0; j < 8; ++j) {
        float v = T[q * 8 + j][px2];
        _Float16 h, l;
        split2(v, h, l);
        hs[j] = h; ls[j] = l;
      }
      *(f16x8*)&oHp[oa] = hs;
      *(f16x8*)&oLp[oa] = ls;
    }
    __syncthreads();
  }
}

// ---------------- MFMA implicit-GEMM 3x3 conv: NWAVES waves, wave = (ms,os) quadrant ----------------
struct CArgs {
  const _Float16* inH[3]; const _Float16* inL[3];   // fp16 HWC per level
  const _Float16* wH; const _Float16* wL;           // [9][ocw][256]
  _Float16* outH[3]; _Float16* outL[3];             // fp16 HWC outs (mode 0)
  const float* inv; const float* beta;              // BN folded
  float* logits; float* tvals;                      // mode 2
  int ocw; int mode;                                // 0 head, 2 rpn
};

template<int NWAVES, int OSN>
__global__ __launch_bounds__(NWAVES * 64) void conv_mfma_kernel(CArgs a)
{
  __shared__ _Float16 Ph[2][4000], Pl[2][4000];   // 2 bufs x 10x10x(4x8+pad) = 32 KB

  int bt = blockIdx.x;
  int lvl, tile;
  if (bt < 64) { lvl = 0; tile = bt; }
  else if (bt < 80) { lvl = 1; tile = bt - 64; }
  else { lvl = 2; tile = bt - 80; }
  int H = (lvl == 0) ? 64 : ((lvl == 1) ? 32 : 16);
  int HW = H * H;
  int tpr = H >> 3;
  int ty0 = (tile / tpr) * 8, tx0 = (tile % tpr) * 8;
  int img = blockIdx.z;
  int ocb = blockIdx.y * 64;
  const _Float16* inH = a.inH[lvl] + (size_t)img * HW * 256;
  const _Float16* inL = a.inL[lvl] + (size_t)img * HW * 256;

  int tid = threadIdx.x;
  int lane = tid & 63, wid = tid >> 6;
  int os = wid % OSN, ms = wid / OSN;
  int row = lane & 31, khalf = lane >> 5;
  int m0 = ms * 32 + row;
  int aoff = ((m0 >> 3) * 10 + (m0 & 7)) * 40 + khalf * 8;

  f32x16 acc1, acc2;
  #pragma unroll
  for (int j = 0; j < 16; ++j) { acc1[j] = 0.f; acc2[j] = 0.f; }

  auto stage = [&](int icb, int buf) {
    for (int u = tid; u < 400; u += NWAVES * 64) {
      int pxl = u >> 2, icq = u & 3;
      int py = pxl / 10, pxx = pxl - py * 10;
      int gy = ty0 + py - 1, gx = tx0 + pxx - 1;
      int lo = pxl * 40 + icq * 8;
      if ((unsigned)gy < (unsigned)H && (unsigned)gx < (unsigned)H) {
        size_t ga = (size_t)(gy * H + gx) * 256 + icb * 32 + icq * 8;
        *(f16x8*)&Ph[buf][lo] = *(const f16x8*)&inH[ga];
        *(f16x8*)&Pl[buf][lo] = *(const f16x8*)&inL[ga];
      } else {
        f16x8 z;
        #pragma unroll
        for (int j = 0; j < 8; ++j) z[j] = (_Float16)0.f;
        *(f16x8*)&Ph[buf][lo] = z;
        *(f16x8*)&Pl[buf][lo] = z;
      }
    }
  };

  stage(0, 0);
  __syncthreads();

  for (int icb = 0; icb < 8; ++icb) {
    int cur = icb & 1;
    if (icb < 7) stage(icb + 1, cur ^ 1);
    #pragma unroll 3
    for (int dydx = 0; dydx < 9; ++dydx) {
      int dy = dydx / 3, dx = dydx - dy * 3;
      int pshift = (dy * 10 + dx) * 40;
      #pragma unroll
      for (int k2 = 0; k2 < 2; ++k2) {
        size_t ga = ((size_t)(dydx * a.ocw) + ocb + os * 32 + row) * 256
                    + icb * 32 + k2 * 16 + khalf * 8;
        f16x8 bh = *(const f16x8*)&a.wH[ga];
        f16x8 bl = *(const f16x8*)&a.wL[ga];
        int off = aoff + pshift + k2 * 16;
        f16x8 ah = *(const f16x8*)&Ph[cur][off];
        f16x8 al = *(const f16x8*)&Pl[cur][off];
        acc1 = __builtin_amdgcn_mfma_f32_32x32x16_f16(ah, bh, acc1, 0, 0, 0);
        acc2 = __builtin_amdgcn_mfma_f32_32x32x16_f16(ah, bl, acc2, 0, 0, 0);
        acc2 = __builtin_amdgcn_mfma_f32_32x32x16_f16(al, bh, acc2, 0, 0, 0);
      }
    }
    __syncthreads();
  }

  // ---- epilogue: this wave's (ms, os) quadrant ----
  if (a.mode == 0) {
    _Float16* outH = a.outH[lvl] + (size_t)img * HW * 256;
    _Float16* outL = a.outL[lvl] + (size_t)img * HW * 256;
    int oc = ocb + os * 32 + row;
    float iv = a.inv[oc], bb = a.beta[oc];
    #pragma unroll
    for (int r = 0; r < 16; ++r) {
      int ml = (r & 3) + 8 * (r >> 2) + 4 * khalf;
      int m = ms * 32 + ml;
      int y = ty0 + (m >> 3), x = tx0 + (m & 7);
      float v = acc1[r] + acc2[r] * (1.f / 4096.f);
      v = v * iv + bb;
      v = (v >= 0.f) ? v : 0.01f * v;
      _Float16 h, l;
      split2(v, h, l);
      size_t oa = (size_t)(y * H + x) * 256 + oc;
      outH[oa] = h;
      outL[oa] = l;
    }
  } else {
    int oc = ocb + row;   // OSN==1
    if (oc < 15) {
      int abase = (lvl == 0) ? 0 : ((lvl == 1) ? 12288 : 15360);
      #pragma unroll
      for (int r = 0; r < 16; ++r) {
        int ml = (r & 3) + 8 * (r >> 2) + 4 * khalf;
        int m = ms * 32 + ml;
        int y = ty0 + (m >> 3), x = tx0 + (m & 7);
        int gi = img * 16128 + abase + (y * H + x) * 3;
        float v = acc1[r] + acc2[r] * (1.f / 4096.f);
        if (oc < 3) a.logits[gi + oc] = v;
        else { int r2 = oc - 3; a.tvals[(size_t)(gi + (r2 >> 2)) * 4 + (r2 & 3)] = v; }
      }
    }
  }
}

// ---------------- decode helper ----------------
__device__ __forceinline__ void decode_one(const float* __restrict__ anch,
                                           const float* __restrict__ tv, int i,
                                           float& x1, float& y1, float& x2, float& y2)
{
  float t0 = tv[i * 4 + 0], t1 = tv[i * 4 + 1], t2 = tv[i * 4 + 2], t3 = tv[i * 4 + 3];
  float a0 = anch[i * 4 + 0], a1 = anch[i * 4 + 1], a2 = anch[i * 4 + 2], a3 = anch[i * 4 + 3];
  float aw = a2 - a0, ah = a3 - a1;
  float xx = a0 + t0 * aw;
  float yy = a1 + t1 * ah;
  float bw = aw * expf(t2);
  float bh = ah * expf(t3);
  x1 = fminf(fmaxf(xx, 0.f), 512.f);
  y1 = fminf(fmaxf(yy, 0.f), 512.f);
  x2 = fminf(fmaxf(xx + bw, 0.f), 512.f);
  y2 = fminf(fmaxf(yy + bh, 0.f), 512.f);
}

// ---------------- score kernel: keys + 2048-bin hist ----------------
__global__ __launch_bounds__(256) void score_kernel(
    const float* __restrict__ logits, const float* __restrict__ tvals,
    const float* __restrict__ anch0, const float* __restrict__ anch1, const float* __restrict__ anch2,
    unsigned int* __restrict__ skey, unsigned int* __restrict__ hist)
{
  int g = blockIdx.x * 256 + threadIdx.x;
  if (g >= 2 * 16128) return;
  int img = g / 16128, r = g - img * 16128;
  int lvl = (r < 12288) ? 0 : ((r < 15360) ? 1 : 2);
  int abase = (lvl == 0) ? 0 : ((lvl == 1) ? 12288 : 15360);
  int stride = (lvl == 0) ? 8 : ((lvl == 1) ? 16 : 32);
  const float* anch = (lvl == 0) ? anch0 : ((lvl == 1) ? anch1 : anch2);
  int i = r - abase;
  float lv = logits[g];
  float sc = 1.f / (1.f + expf(-lv));
  float x1, y1, x2, y2;
  decode_one(anch, tvals + (size_t)(img * 16128 + abase) * 4, i, x1, y1, x2, y2);
  float minsz = 2.0f * (float)stride;
  bool valid = (sc > 0.5f) && ((x2 - x1) >= minsz) && ((y2 - y1) >= minsz);
  unsigned int key = valid ? __float_as_uint(sc) : 0u;
  skey[g] = key;
  if (valid)
    atomicAdd(&hist[(img * 3 + lvl) * 2048 + ((key & 0xFFFFFFu) >> 13)], 1u);
}

// ---------------- postproc: bin-threshold -> collect -> rank-sort -> ballot NMS -> outputs ----------------
__global__ __launch_bounds__(256) void postproc_kernel(
    const float* __restrict__ tvals,
    const float* __restrict__ anch0, const float* __restrict__ anch1, const float* __restrict__ anch2,
    const unsigned int* __restrict__ skey, const unsigned int* __restrict__ hist,
    float* __restrict__ dout, int* __restrict__ coords)
{
  int lvl = blockIdx.x, img = blockIdx.y;
  int N = (lvl == 0) ? 12288 : ((lvl == 1) ? 3072 : 768);
  int stride = (lvl == 0) ? 8 : ((lvl == 1) ? 16 : 32);
  int abase = (lvl == 0) ? 0 : ((lvl == 1) ? 12288 : 15360);
  const float* anch = (lvl == 0) ? anch0 : ((lvl == 1) ? anch1 : anch2);
  const float* tv = tvals + (size_t)(img * 16128 + abase) * 4;
  const unsigned int* sk = skey + img * 16128 + abase;
  int tx = threadIdx.x;

  __shared__ int tot[256];
  __shared__ int sh_bin, sh_V;
  __shared__ ull slist[1024];
  __shared__ int scnt;
  __shared__ ull skey64[256];
  __shared__ float bx0[256], bx1[256], bx2[256], bx3[256], bar[256], bsc[256];
  __shared__ ull colT[256][4];
  __shared__ ull kinit[4], kfin[4];
  __shared__ unsigned char bkeepArr[256];
  __shared__ int sel[32];

  // ---- threshold bin from precomputed hist ----
  const unsigned int* hp = hist + (img * 3 + lvl) * 2048;
  unsigned int hloc[8];
  #pragma unroll
  for (int j = 0; j < 8; ++j) hloc[j] = hp[tx * 8 + j];
  int sl[9]; sl[8] = 0;
  #pragma unroll
  for (int j = 7; j >= 0; --j) sl[j] = sl[j + 1] + (int)hloc[j];
  tot[tx] = sl[0];
  if (tx == 0) { sh_bin = 2048; scnt = 0; }
  __syncthreads();
  int T = 0;
  for (int b = 0; b < 256; ++b) T += (b > tx) ? tot[b] : 0;
  if (tx == 0) sh_V = T + sl[0];
  __syncthreads();
  int V = sh_V;
  int needed = (V < 256) ? V : 256;
  if (needed > 0) {
    #pragma unroll
    for (int j = 0; j < 8; ++j) {
      int suf = T + sl[j];
      int sufn = (j < 7) ? (T + sl[j + 1]) : T;
      if (suf >= needed && sufn < needed) sh_bin = tx * 8 + j;
    }
  }
  #pragma unroll
  for (int q = 0; q < 4; ++q) slist[tx + q * 256] = 0ull;
  __syncthreads();
  int Bstar = sh_bin;

  // ---- collect candidates (bin >= Bstar), vectorized ----
  if (needed > 0) {
    const uint4* sk4 = (const uint4*)sk;
    for (int i4 = tx; i4 < (N >> 2); i4 += 256) {
      uint4 v4 = sk4[i4];
      unsigned int vv[4] = {v4.x, v4.y, v4.z, v4.w};
      #pragma unroll
      for (int q = 0; q < 4; ++q) {
        unsigned int v = vv[q];
        if (v != 0u && (int)((v & 0xFFFFFFu) >> 13) >= Bstar) {
          int p = atomicAdd(&scnt, 1);
          if (p < 1024)
            slist[p] = ((ull)v << 32) | (ull)(0xFFFFFFFFu - (unsigned)(i4 * 4 + q));
        }
      }
    }
  }
  __syncthreads();
  int M = scnt < 1024 ? scnt : 1024;

  // ---- rank sort (keys unique): sorted[rank] = key, keep top 256 ----
  skey64[tx] = 0ull;
  __syncthreads();
  for (int it = tx; it < M; it += 256) {
    ull K = slist[it];
    int rank = 0;
    for (int j = 0; j < M; ++j) rank += (slist[j] > K) ? 1 : 0;
    if (rank < 256) skey64[rank] = K;
  }
  __syncthreads();

  // ---- decode 256 slots ----
  {
    ull key = skey64[tx];
    float x1 = 0.f, y1 = 0.f, x2 = 0.f, y2 = 0.f, sc = 0.f;
    if (key != 0ull) {
      sc = __uint_as_float((unsigned int)(key >> 32));
      int idx = (int)(0xFFFFFFFFu - (unsigned int)(key & 0xFFFFFFFFull));
      decode_one(anch, tv, idx, x1, y1, x2, y2);
    }
    bx0[tx] = x1; bx1[tx] = y1; bx2[tx] = x2; bx3[tx] = y2;
    bsc[tx] = sc;
    bar[tx] = (x2 - x1 + 1.f) * (y2 - y1 + 1.f);
    ull b = __ballot(sc > 0.5f);
    if ((tx & 63) == 0) kinit[tx >> 6] = b;
  }
  __syncthreads();

  // ---- column masks: colT[j][w] bits i (word w) with i<j and IoU(i,j)>0.3 ----
  {
    float xj1 = bx0[tx], yj1 = bx1[tx], xj2 = bx2[tx], yj2 = bx3[tx], aj = bar[tx];
    #pragma unroll
    for (int w = 0; w < 4; ++w) {
      ull rr = 0ull;
      int j0 = w * 64;
      int ie = (tx < j0 + 64) ? tx : (j0 + 64);
      for (int i = j0; i < ie; ++i) {
        float xx1 = fmaxf(xj1, bx0[i]);
        float yy1 = fmaxf(yj1, bx1[i]);
        float xx2 = fminf(xj2, bx2[i]);
        float yy2 = fminf(yj2, bx3[i]);
        float ww = fmaxf(0.f, xx2 - xx1 + 1.f);
        float hh = fmaxf(0.f, yy2 - yy1 + 1.f);
        float inter = ww * hh;
        float ovr = inter / (aj + bar[i] - inter);
        rr |= (ovr > 0.3f) ? (1ull << (i & 63)) : 0ull;
      }
      colT[tx][w] = rr;
    }
  }
  __syncthreads();

  // ---- wave-0 ballot greedy: visit only live boxes in ascending order ----
  if (tx < 64) {
    int l = tx;
    ull cm[4][4];
    #pragma unroll
    for (int c = 0; c < 4; ++c)
      #pragma unroll
      for (int w = 0; w < 4; ++w) cm[c][w] = colT[l + 64 * c][w];
    int av[4];
    #pragma unroll
    for (int c = 0; c < 4; ++c) av[c] = (int)((kinit[c] >> l) & 1ull);
    for (int cw = 0; cw < 4; ++cw) {
      ull rem = __ballot(av[cw] != 0);
      while (rem) {
        int ib = __builtin_ctzll(rem);
        #pragma unroll
        for (int c = 0; c < 4; ++c) {
          int sup = (int)((cm[c][cw] >> ib) & 1ull);
          av[c] &= sup ^ 1;
        }
        ull ready = __ballot(av[cw] != 0);
        rem = (ib == 63) ? 0ull : (ready & (~0ull << (ib + 1)));
      }
    }
    #pragma unroll
    for (int c = 0; c < 4; ++c) {
      ull bw = __ballot(av[c] != 0);
      if (l == 0) kfin[c] = bw;
      bkeepArr[l + 64 * c] = (unsigned char)av[c];
    }
  }
  __syncthreads();

  // ---- parallel stable order via popcount ranks ----
  {
    int r = tx;
    int m = bkeepArr[r];
    int K = 0, before = 0;
    #pragma unroll
    for (int c = 0; c < 4; ++c) {
      int pc = __popcll(kfin[c]);
      K += pc;
      if (r >= (c + 1) * 64) before += pc;
      else if (r > c * 64) before += __popcll(kfin[c] & ((1ull << (r - c * 64)) - 1ull));
    }
    int rank = m ? before : (K + r - before);
    if (rank < 32) sel[rank] = r;
  }
  __syncthreads();

  if (tx < 32) {
    int r = sel[tx];
    int m = bkeepArr[r];
    int ob = (img * 3 + lvl) * 32 + tx;
    float d0 = 0.f, d1 = 0.f, d2 = 0.f, d3 = 0.f, d4 = 0.f;
    int c0 = 0, c1 = 0, c2 = 2, c3 = 2;
    if (m) {
      d0 = bx0[r]; d1 = bx1[r]; d2 = bx2[r]; d3 = bx3[r]; d4 = bsc[r];
      c0 = ((int)d0) / stride; c1 = ((int)d1) / stride;
      c2 = ((int)d2) / stride; c3 = ((int)d3) / stride;
    }
    dout[ob * 5 + 0] = d0; dout[ob * 5 + 1] = d1; dout[ob * 5 + 2] = d2;
    dout[ob * 5 + 3] = d3; dout[ob * 5 + 4] = d4;
    dout[960 + ob] = m ? 1.f : 0.f;
    coords[ob * 5 + 0] = c0; coords[ob * 5 + 1] = c1;
    coords[ob * 5 + 2] = c2; coords[ob * 5 + 3] = c3;
    coords[ob * 5 + 4] = m;
  }
}

// ---------------- ROI adaptive 7x7 maxpool: one block per (roi, bin) ----------------
__global__ __launch_bounds__(256) void roipool_kernel(
    const _Float16* __restrict__ fh0, const _Float16* __restrict__ fl0,
    const _Float16* __restrict__ fh1, const _Float16* __restrict__ fl1,
    const _Float16* __restrict__ fh2, const _Float16* __restrict__ fl2,
    const int* __restrict__ coords, float* __restrict__ dout)
{
  int bx = blockIdx.x;
  int slot = bx / 49, bin = bx - slot * 49;
  int yi = bin / 7, xi = bin - yi * 7;
  int lvl = blockIdx.y, img = blockIdx.z;
  int ob = (img * 3 + lvl) * 32 + slot;
  int c = threadIdx.x;
  const int* cw = coords + ob * 5;
  float* outp = dout + 1152 + (size_t)ob * 256 * 49 + (size_t)c * 49 + yi * 7 + xi;
  int m = cw[4];
  if (!m) { *outp = 0.f; return; }
  int H = (lvl == 0) ? 64 : ((lvl == 1) ? 32 : 16);
  const _Float16* fh = ((lvl == 0) ? fh0 : ((lvl == 1) ? fh1 : fh2)) + (size_t)img * H * H * 256;
  const _Float16* fl = ((lvl == 0) ? fl0 : ((lvl == 1) ? fl1 : fl2)) + (size_t)img * H * H * 256;
  int lox = cw[0], loy = cw[1], hix = cw[2], hiy = cw[3];
  int Lx = hix - lox, Ly = hiy - loy;
  int ys = loy + (yi * Ly) / 7;
  int ye = loy + ((yi + 1) * Ly + 6) / 7;
  int xs = lox + (xi * Lx) / 7;
  int xe = lox + ((xi + 1) * Lx + 6) / 7;
  float mx = -3.402823466e+38f;
  for (int y = ys; y < ye; ++y) {
    size_t rowb = ((size_t)y * H) * 256 + c;
    for (int x = xs; x < xe; ++x) {
      size_t idx = rowb + (size_t)x * 256;
      float v = (float)fh[idx] + (float)fl[idx] * (1.f / 4096.f);
      mx = fmaxf(mx, v);
    }
  }
  *outp = mx;
}

// ---------------- host ----------------
extern "C" void kernel_launch(void* const* d_in, const int* in_sizes, int n_in,
                              void* d_out, int out_size, void* d_ws, size_t ws_size,
                              hipStream_t stream)
{
  (void)in_sizes; (void)n_in; (void)out_size; (void)ws_size;
  char* ws = (char*)d_ws;
  const float* layer2 = (const float*)d_in[0];
  const float* layer3 = (const float*)d_in[1];
  const float* layer4 = (const float*)d_in[2];
  const float* anch2  = (const float*)d_in[3];
  const float* anch3  = (const float*)d_in[4];
  const float* anch4  = (const float*)d_in[5];
  const float* hw1 = (const float*)d_in[6];
  const float* hg1 = (const float*)d_in[7];
  const float* hb1 = (const float*)d_in[8];
  const float* hm1 = (const float*)d_in[9];
  const float* hv1 = (const float*)d_in[10];
  const float* hw2 = (const float*)d_in[11];
  const float* hg2 = (const float*)d_in[12];
  const float* hb2 = (const float*)d_in[13];
  const float* hm2 = (const float*)d_in[14];
  const float* hv2 = (const float*)d_in[15];
  const float* clsw = (const float*)d_in[16];
  const float* locw = (const float*)d_in[17];
  float* dout = (float*)d_out;

  _Float16* i0H = (_Float16*)(ws + OFF_I0H);
  _Float16* i0L = (_Float16*)(ws + OFF_I0L);
  _Float16* i1H = (_Float16*)(ws + OFF_I1H);
  _Float16* i1L = (_Float16*)(ws + OFF_I1L);
  _Float16* i2H = (_Float16*)(ws + OFF_I2H);
  _Float16* i2L = (_Float16*)(ws + OFF_I2L);
  float* l3f = (float*)(ws + OFF_L3F);
  _Float16* h0H = (_Float16*)(ws + OFF_H0H);
  _Float16* h0L = (_Float16*)(ws + OFF_H0L);
  _Float16* h1H = (_Float16*)(ws + OFF_H1H);
  _Float16* h1L = (_Float16*)(ws + OFF_H1L);
  _Float16* h2H = (_Float16*)(ws + OFF_H2H);
  _Float16* h2L = (_Float16*)(ws + OFF_H2L);
  float* logits = (float*)(ws + OFF_LOGITS);
  float* tvals  = (float*)(ws + OFF_TVALS);
  unsigned int* skey = (unsigned int*)(ws + OFF_SKEY);
  int* coords = (int*)(ws + OFF_COORDS);
  float* bn = (float*)(ws + OFF_BN);
  float* inv1 = bn; float* beta1 = bn + 256; float* inv2 = bn + 512; float* beta2 = bn + 768;
  unsigned int* hist = (unsigned int*)(ws + OFF_HIST);

  prep_bn_kernel<<<1, 256, 0, stream>>>(hg1, hb1, hm1, hv1, hg2, hb2, hm2, hv2,
                                        inv1, beta1, inv2, beta2);
  zero_hist_kernel<<<48, 256, 0, stream>>>(hist);
  prep_w_kernel<<<2048, 256, 0, stream>>>(hw1, hw2, clsw, locw, ws);

  fuse_kernel<<<dim3(4, 2), 256, 0, stream>>>(layer4, nullptr, nullptr, i2H, i2L, 16, 4);
  fuse_kernel<<<dim3(16, 2), 256, 0, stream>>>(layer3, layer4, l3f, i1H, i1L, 32, 5);
  fuse_kernel<<<dim3(64, 2), 256, 0, stream>>>(layer2, l3f, nullptr, i0H, i0L, 64, 6);

  CArgs c1;
  c1.inH[0] = i0H; c1.inH[1] = i1H; c1.inH[2] = i2H;
  c1.inL[0] = i0L; c1.inL[1] = i1L; c1.inL[2] = i2L;
  c1.wH = (const _Float16*)(ws + OFF_W1H); c1.wL = (const _Float16*)(ws + OFF_W1L);
  c1.outH[0] = h0H; c1.outH[1] = h1H; c1.outH[2] = h2H;
  c1.outL[0] = h0L; c1.outL[1] = h1L; c1.outL[2] = h2L;
  c1.inv = inv1; c1.beta = beta1;
  c1.logits = nullptr; c1.tvals = nullptr;
  c1.ocw = 256; c1.mode = 0;
  conv_mfma_kernel<4, 2><<<dim3(84, 4, 2), 256, 0, stream>>>(c1);

  _Float16* f0H = i0H; _Float16* f0L = i0L;
  _Float16* f1H = i1H; _Float16* f1L = i1L;
  _Float16* f2H = i2H; _Float16* f2L = i2L;

  CArgs c2;
  c2.inH[0] = h0H; c2.inH[1] = h1H; c2.inH[2] = h2H;
  c2.inL[0] = h0L; c2.inL[1] = h1L; c2.inL[2] = h2L;
  c2.wH = (const _Float16*)(ws + OFF_W2H); c2.wL = (const _Float16*)(ws + OFF_W2L);
  c2.outH[0] = f0H; c2.outH[1] = f1H; c2.outH[2] = f2H;
  c2.outL[0] = f0L; c2.outL[1] = f1L; c2.outL[2] = f2L;
  c2.inv = inv2; c2.beta = beta2;
  c2.logits = nullptr; c2.tvals = nullptr;
  c2.ocw = 256; c2.mode = 0;
  conv_mfma_kernel<4, 2><<<dim3(84, 4, 2), 256, 0, stream>>>(c2);

  CArgs cr;
  cr.inH[0] = f0H; cr.inH[1] = f1H; cr.inH[2] = f2H;
  cr.inL[0] = f0L; cr.inL[1] = f1L; cr.inL[2] = f2L;
  cr.wH = (const _Float16*)(ws + OFF_WRH); cr.wL = (const _Float16*)(ws + OFF_WRL);
  cr.outH[0] = nullptr; cr.outH[1] = nullptr; cr.outH[2] = nullptr;
  cr.outL[0] = nullptr; cr.outL[1] = nullptr; cr.outL[2] = nullptr;
  cr.inv = nullptr; cr.beta = nullptr;
  cr.logits = logits; cr.tvals = tvals;
  cr.ocw = 32; cr.mode = 2;
  conv_mfma_kernel<2, 1><<<dim3(84, 1, 2), 128, 0, stream>>>(cr);

  score_kernel<<<126, 256, 0, stream>>>(logits, tvals, anch2, anch3, anch4, skey, hist);
  postproc_kernel<<<dim3(3, 2), 256, 0, stream>>>(tvals, anch2, anch3, anch4, skey, hist, dout, coords);
  roipool_kernel<<<dim3(32 * 49, 3, 2), 256, 0, stream>>>(f0H, f0L, f1H, f1L, f2H, f2L, coords, dout);
}